// Round 2
// baseline (500.801 us; speedup 1.0000x reference)
//
#include <hip/hip_runtime.h>
#include <hip/hip_bf16.h>
#include <stdint.h>

typedef unsigned short u16;
typedef __bf16 bf16_t;
typedef bf16_t bf16x8 __attribute__((ext_vector_type(8)));
typedef float f32x4 __attribute__((ext_vector_type(4)));

__device__ __forceinline__ u16 f2b(float f) {
    union { float f; uint32_t i; } v; v.f = f;
    uint32_t r = v.i + 0x7FFFu + ((v.i >> 16) & 1u);
    return (u16)(r >> 16);
}
__device__ __forceinline__ uint32_t pk2(float a, float b) {
    __hip_bfloat162 h = __float22bfloat162_rn(float2{a, b});
    return *(const uint32_t*)&h;
}
__device__ __forceinline__ uint4 pack8(float4 lo, float4 hi) {
    uint4 r;
    r.x = pk2(lo.x, lo.y); r.y = pk2(lo.z, lo.w);
    r.z = pk2(hi.x, hi.y); r.w = pk2(hi.z, hi.w);
    return r;
}
// async global->LDS DMA, 16B per lane (m97 idiom: LDS dst linear in lane)
__device__ __forceinline__ void async16(const u16* g, u16* l) {
    __builtin_amdgcn_global_load_lds(
        (const __attribute__((address_space(1))) uint32_t*)g,
        (__attribute__((address_space(3))) uint32_t*)l,
        16, 0, 0);
}

// ---------------- GEMM core: C[M,N] = X[M,1024] @ W[1024,N] + bias ----------------
// WT = W^T bf16 [N][K]. 128x128 tile, BK=64, 2x2 wave quadrants, 4x4 16x16x32 frags.
// LDS tiles 128x64, unpadded, XOR-swizzled: physical 16B-block pb of row r holds
// logical block pb^(r&7) -> frag b128 reads are 2-way (free). B staged via async16
// (zero VGPRs); A staged via transient f32->bf16 VGPR pass when XF32 (qkv) or
// async16 when bf16 (oproj). No registers held across the compute phase (R5 spill fix).
// mode 0: bf16 scatter [B,H,S,D]; mode 1: f32 row-major; mode 2: bf16 V^T [BH,64,2048]
template<bool XF32>
__device__ __forceinline__ void gemm128(const void* __restrict__ Xv,
                                        const u16* __restrict__ WT,
                                        const float* __restrict__ bias,
                                        u16* __restrict__ dstb,
                                        float* __restrict__ dstf, int mode)
{
    __shared__ __align__(16) u16 As[128 * 64];
    __shared__ __align__(16) u16 Bs[128 * 64];
    const int t    = threadIdx.x;
    const int lane = t & 63;
    const int quad = lane >> 4;
    const int l15  = lane & 15;
    const int m0 = blockIdx.y * 128;
    const int n0 = blockIdx.x * 128;
    const int wave = t >> 6;
    const int wm = (wave >> 1) * 64;
    const int wn = (wave & 1) * 64;

    f32x4 acc[4][4];
#pragma unroll
    for (int i = 0; i < 4; i++)
#pragma unroll
        for (int j = 0; j < 4; j++)
#pragma unroll
            for (int r = 0; r < 4; r++) acc[i][j][r] = 0.0f;

    // staging chunk map: ci = c*256+t; row r=ci>>3, physical block pb=ci&7,
    // logical (global) block lb = pb ^ (r&7)
    int rr[4], lb[4];
#pragma unroll
    for (int c = 0; c < 4; c++) {
        const int ci = c * 256 + t;
        rr[c] = ci >> 3;
        lb[c] = (ci & 7) ^ (rr[c] & 7);
    }

    for (int kt = 0; kt < 1024; kt += 64) {
        __syncthreads();                    // (a) prior tile's frag reads complete
#pragma unroll
        for (int c = 0; c < 4; c++)         // B: async DMA, no VGPRs
            async16(WT + (n0 + rr[c]) * 1024 + kt + lb[c] * 8, &Bs[(c * 256 + t) * 8]);
        if (XF32) {                         // A: f32 load -> bf16 pack -> LDS
#pragma unroll
            for (int c = 0; c < 4; c++) {
                const float* g = (const float*)Xv + (m0 + rr[c]) * 1024 + kt + lb[c] * 8;
                const float4 lo = *(const float4*)g;
                const float4 hi = *(const float4*)(g + 4);
                *(uint4*)&As[(c * 256 + t) * 8] = pack8(lo, hi);
            }
        } else {
#pragma unroll
            for (int c = 0; c < 4; c++)
                async16((const u16*)Xv + (m0 + rr[c]) * 1024 + kt + lb[c] * 8,
                        &As[(c * 256 + t) * 8]);
        }
        __syncthreads();                    // (b) vmcnt drained + staging visible

#pragma unroll
        for (int kk = 0; kk < 64; kk += 32) {
            bf16x8 af[4], bfv[4];
#pragma unroll
            for (int i = 0; i < 4; i++) {
                const int ra = wm + i * 16 + l15;
                const int rb2 = wn + i * 16 + l15;
                af[i]  = *(const bf16x8*)&As[ra * 64 + (((kk >> 3) + quad) ^ (l15 & 7)) * 8];
                bfv[i] = *(const bf16x8*)&Bs[rb2 * 64 + (((kk >> 3) + quad) ^ (l15 & 7)) * 8];
            }
#pragma unroll
            for (int i = 0; i < 4; i++)
#pragma unroll
                for (int j = 0; j < 4; j++)
                    acc[i][j] = __builtin_amdgcn_mfma_f32_16x16x32_bf16(af[i], bfv[j], acc[i][j], 0, 0, 0);
        }
    }

    // epilogue: C row = quad*4 + r, col = lane&15 (HW-verified R4)
#pragma unroll
    for (int i = 0; i < 4; i++) {
        const int rb = m0 + wm + i * 16 + quad * 4;
#pragma unroll
        for (int j = 0; j < 4; j++) {
            const int col = n0 + wn + j * 16 + l15;
            const float bias_v = bias[col];
            if (mode == 2) {
                // V^T direct store: 4 consecutive s at fixed (h,d) -> packed b64
                const int b = rb >> 11, s = rb & 2047;
                const int h = col >> 6, d = col & 63;
                uint2 pk;
                pk.x = pk2(acc[i][j][0] + bias_v, acc[i][j][1] + bias_v);
                pk.y = pk2(acc[i][j][2] + bias_v, acc[i][j][3] + bias_v);
                *(uint2*)&dstb[((b * 16 + h) * 64 + d) * 2048 + s] = pk;
            } else {
#pragma unroll
                for (int r = 0; r < 4; r++) {
                    const float v = acc[i][j][r] + bias_v;
                    const int gm = rb + r;
                    if (mode == 0) {
                        const int b = gm >> 11, s = gm & 2047;
                        const int h = col >> 6, d = col & 63;
                        dstb[((b * 16 + h) * 2048 + s) * 64 + d] = f2b(v);
                    } else {
                        dstf[gm * 1024 + col] = v;
                    }
                }
            }
        }
    }
}

__global__ __launch_bounds__(256)
void qkv_kernel(const float* __restrict__ q_in, const float* __restrict__ k_in,
                const float* __restrict__ v_in, const u16* __restrict__ WT,
                const float* __restrict__ bq, const float* __restrict__ bk,
                const float* __restrict__ bv,
                u16* __restrict__ Qo, u16* __restrict__ Ko, u16* __restrict__ VTo)
{
    const int z = blockIdx.z;
    const float* X   = (z == 0) ? q_in : (z == 1) ? k_in : v_in;
    const u16* wt    = WT + ((z == 0) ? 2 : (z == 1) ? 1 : 0) * (1024 * 1024);
    const float* bias= (z == 0) ? bq : (z == 1) ? bk : bv;
    u16* dst         = (z == 0) ? Qo : (z == 1) ? Ko : VTo;
    gemm128<true>(X, wt, bias, dst, nullptr, (z == 2) ? 2 : 0);
}

__global__ __launch_bounds__(256)
void oproj_kernel(const u16* __restrict__ AO, const u16* __restrict__ WT,
                  const float* __restrict__ bo, float* __restrict__ out)
{
    gemm128<false>(AO, WT + 3 * 1024 * 1024, bo, nullptr, out, 1);
}

// ---------------- weight transpose+cvt: W[1024 k][1024 n] f32 -> WT[n][k] bf16 ----
__global__ void transpose_w(const float* __restrict__ Wv, const float* __restrict__ Wk,
                            const float* __restrict__ Wq, const float* __restrict__ Wo,
                            u16* __restrict__ WT)
{
    __shared__ u16 tile[64][65];
    const int z = blockIdx.z;
    const float* W = (z == 0) ? Wv : (z == 1) ? Wk : (z == 2) ? Wq : Wo;
    u16* dst = WT + z * 1024 * 1024;
    const int r0 = blockIdx.y * 64, c0 = blockIdx.x * 64;
    const int col = threadIdx.x & 63, rb = threadIdx.x >> 6;
#pragma unroll
    for (int r = rb; r < 64; r += 4) tile[r][col] = f2b(W[(r0 + r) * 1024 + c0 + col]);
    __syncthreads();
#pragma unroll
    for (int r = rb; r < 64; r += 4) dst[(c0 + r) * 1024 + r0 + col] = tile[col][r];
}

// ---------------- flash attention (transposed): Tq=64/block, Tk=128 KV tiles -------
// S^T = K·Q^T -> per-lane online softmax (lane owns one q-row, 2 shuffles).
// K/V staged via async16 into unpadded XOR-swizzled LDS (no prefetch regs -> no
// spill). O^T = V^T·P^T.
// R6: Q lives in 8 VGPRs/lane -> Qs LDS eliminated.
// R7: Ps ALIASES Ks (phase-disjoint: Ks only read in QK^T, Ps only used in PV).
// Requires barrier (c) between last Ks read and first Ps write. LDS 49152->32768
// -> 5 blocks/CU (VGPR 80 <= 102 cap for 5 waves/SIMD). 3 barriers/iter.
__global__ __launch_bounds__(256, 5)
void attn_kernel(const u16* __restrict__ Q, const u16* __restrict__ K,
                 const u16* __restrict__ VT, u16* __restrict__ AO)
{
    __shared__ __align__(16) u16 KPs[128 * 64];   // Ks (swizzle r&7) / Ps (swizzle r&15)
    __shared__ __align__(16) u16 Vts[64 * 128];   // swizzle r&15

    const int t    = threadIdx.x;
    const int lane = t & 63;
    const int wave = t >> 6;
    const int quad = lane >> 4;
    const int l15  = lane & 15;
    const int bh = blockIdx.y;
    const int qt = blockIdx.x;

    const u16* Qg = Q + (bh * 2048 + qt * 64) * 64;
    const u16* Kg = K + bh * 2048 * 64;
    const u16* Vg = VT + bh * 64 * 2048;

    // Q fragments in registers: lane needs row (wave*16+l15), cols quad*8 + {0..7}
    // at kk=0 and kk=32; fold 0.125*log2(e) so softmax runs in exp2 domain.
    bf16x8 bqr[2];
    {
        const u16* qrow = Qg + (wave * 16 + l15) * 64 + quad * 8;
#pragma unroll
        for (int c = 0; c < 2; c++) {
            uint4 dv = *(const uint4*)(qrow + c * 32);
            u16 tmp[8];
            *(uint4*)tmp = dv;
            float f[8];
#pragma unroll
            for (int i = 0; i < 8; i++) {
                union { float f; uint32_t u; } x; x.u = ((uint32_t)tmp[i]) << 16;
                f[i] = x.f * 0.18033688f;   // 0.125 * log2e
            }
            uint4 pk;
            pk.x = pk2(f[0], f[1]); pk.y = pk2(f[2], f[3]);
            pk.z = pk2(f[4], f[5]); pk.w = pk2(f[6], f[7]);
            bqr[c] = *(bf16x8*)&pk;
        }
    }

    f32x4 o[4];
#pragma unroll
    for (int dj = 0; dj < 4; dj++)
#pragma unroll
        for (int r = 0; r < 4; r++) o[dj][r] = 0.0f;
    float m_st = -1.0e30f, l_st = 0.0f;

    // staging maps (linear LDS chunk ci = c*256+t)
    int krr[4], klb[4], vrr[4], vlb[4];
#pragma unroll
    for (int c = 0; c < 4; c++) {
        const int ci = c * 256 + t;
        krr[c] = ci >> 3;  klb[c] = (ci & 7)  ^ (krr[c] & 7);
        vrr[c] = ci >> 4;  vlb[c] = (ci & 15) ^ (vrr[c] & 15);
    }

    for (int kv = 0; kv < 16; kv++) {
        const int j0 = kv * 128;
        __syncthreads();   // (a) prev tile's PV reads (KPs-as-Ps, Vts) done
#pragma unroll
        for (int c = 0; c < 4; c++) {
            async16(Kg + (j0 + krr[c]) * 64 + klb[c] * 8, &KPs[(c * 256 + t) * 8]);
            async16(Vg + vrr[c] * 2048 + j0 + vlb[c] * 8, &Vts[(c * 256 + t) * 8]);
        }
        __syncthreads();   // (b) DMA drained (vmcnt 0 before barrier) + visible

        // S^T = K·Q^T : A-frags = K rows (kv), B-frag = this wave's q-rows (regs)
        f32x4 s[8];
#pragma unroll
        for (int n = 0; n < 8; n++)
#pragma unroll
            for (int r = 0; r < 4; r++) s[n][r] = 0.0f;
#pragma unroll
        for (int kk = 0; kk < 64; kk += 32) {
            const bf16x8 bq = bqr[kk >> 5];
#pragma unroll
            for (int n = 0; n < 8; n++) {
                const bf16x8 ak = *(const bf16x8*)
                    &KPs[(n * 16 + l15) * 64 + (((kk >> 3) + quad) ^ (l15 & 7)) * 8];
                s[n] = __builtin_amdgcn_mfma_f32_16x16x32_bf16(ak, bq, s[n], 0, 0, 0);
            }
        }
        __syncthreads();   // (c) ALL waves' Ks reads done before Ps overwrites KPs

        // per-lane online softmax (q-row = l15 of this wave's 16); max3 trees
        float mxn[8];
#pragma unroll
        for (int n = 0; n < 8; n++)
            mxn[n] = fmaxf(fmaxf(s[n][0], s[n][1]), fmaxf(s[n][2], s[n][3]));
        float mx = fmaxf(fmaxf(fmaxf(mxn[0], mxn[1]), fmaxf(mxn[2], mxn[3])),
                         fmaxf(fmaxf(mxn[4], mxn[5]), fmaxf(mxn[6], mxn[7])));
        mx = fmaxf(mx, __shfl_xor(mx, 16));
        mx = fmaxf(mx, __shfl_xor(mx, 32));
        const float mnew = fmaxf(m_st, mx);
        const float alpha = exp2f(m_st - mnew);
        m_st = mnew;
        float sum = 0.0f;
#pragma unroll
        for (int n = 0; n < 8; n++)
#pragma unroll
            for (int r = 0; r < 4; r++) {
                const float p = exp2f(s[n][r] - m_st);
                s[n][r] = p;
                sum += p;
            }
        sum += __shfl_xor(sum, 16);
        sum += __shfl_xor(sum, 32);
        l_st = l_st * alpha + sum;
#pragma unroll
        for (int dj = 0; dj < 4; dj++)
#pragma unroll
            for (int r = 0; r < 4; r++) o[dj][r] *= alpha;

        // P^T[qrow][kv] -> swizzled LDS (aliasing Ks), packed b64
#pragma unroll
        for (int n = 0; n < 8; n++) {
            const int pbw = ((2 * n + (quad >> 1)) ^ l15);
            uint2 pk;
            pk.x = pk2(s[n][0], s[n][1]);
            pk.y = pk2(s[n][2], s[n][3]);
            *(uint2*)&KPs[(wave * 16 + l15) * 128 + pbw * 8 + (quad & 1) * 4] = pk;
        }
        asm volatile("s_waitcnt lgkmcnt(0)" ::: "memory");  // wave-private RAW fence

        // O^T += V^T·P^T
#pragma unroll
        for (int ks = 0; ks < 4; ks++) {
#pragma unroll
            for (int dj = 0; dj < 4; dj++) {
                const bf16x8 av = *(const bf16x8*)
                    &Vts[(dj * 16 + l15) * 128 + ((ks * 4 + quad) ^ l15) * 8];
                const bf16x8 bp = *(const bf16x8*)
                    &KPs[(wave * 16 + l15) * 128 + ((ks * 4 + quad) ^ l15) * 8];
                o[dj] = __builtin_amdgcn_mfma_f32_16x16x32_bf16(av, bp, o[dj], 0, 0, 0);
            }
        }
    }

    // epilogue: O^T[d = dj*16+quad*4+r][qrow = l15]; write bf16 [B,S,E] packed b64
    const int b = bh >> 4, h = bh & 15;
    const int sq = qt * 64 + wave * 16 + l15;
    const float inv = 1.0f / l_st;
#pragma unroll
    for (int dj = 0; dj < 4; dj++) {
        uint2 pk;
        pk.x = pk2(o[dj][0] * inv, o[dj][1] * inv);
        pk.y = pk2(o[dj][2] * inv, o[dj][3] * inv);
        *(uint2*)&AO[(b * 2048 + sq) * 1024 + h * 64 + dj * 16 + quad * 4] = pk;
    }
}

extern "C" void kernel_launch(void* const* d_in, const int* in_sizes, int n_in,
                              void* d_out, int out_size, void* d_ws, size_t ws_size,
                              hipStream_t stream)
{
    (void)in_sizes; (void)n_in; (void)out_size; (void)ws_size;
    const float* value = (const float*)d_in[0];
    const float* key_  = (const float*)d_in[1];
    const float* query = (const float*)d_in[2];
    const float* Wv = (const float*)d_in[3];
    const float* bv = (const float*)d_in[4];
    const float* Wk = (const float*)d_in[5];
    const float* bk = (const float*)d_in[6];
    const float* Wq = (const float*)d_in[7];
    const float* bq = (const float*)d_in[8];
    const float* Wo = (const float*)d_in[9];
    const float* bo = (const float*)d_in[10];

    u16* ws = (u16*)d_ws;
    u16* WT = ws;                          // 4 x 1M bf16 (order: v,k,q,o)
    u16* Q  = ws + 4 * 1024 * 1024;        // 8M bf16 [B,H,S,D]
    u16* K  = Q + 8 * 1024 * 1024;         // 8M [B,H,S,D]
    u16* VT = K + 8 * 1024 * 1024;         // 8M [B,H,D,S] (written directly by qkv)
    u16* AO = VT + 8 * 1024 * 1024;        // 8M [B*S, E]   (total 72 MB, proven)

    transpose_w<<<dim3(16, 16, 4), dim3(256), 0, stream>>>(Wv, Wk, Wq, Wo, WT);
    qkv_kernel<<<dim3(8, 64, 3), dim3(256), 0, stream>>>(query, key_, value, WT,
                                                         bq, bk, bv, Q, K, VT);
    attn_kernel<<<dim3(32, 64), dim3(256), 0, stream>>>(Q, K, VT, AO);
    oproj_kernel<<<dim3(8, 64, 1), dim3(256), 0, stream>>>(AO, WT, bo, (float*)d_out);
}

// Round 3
// 427.276 us; speedup vs baseline: 1.1721x; 1.1721x over previous
//
#include <hip/hip_runtime.h>
#include <hip/hip_bf16.h>
#include <stdint.h>

typedef unsigned short u16;
typedef __bf16 bf16_t;
typedef bf16_t bf16x8 __attribute__((ext_vector_type(8)));
typedef float f32x4 __attribute__((ext_vector_type(4)));

__device__ __forceinline__ u16 f2b(float f) {
    union { float f; uint32_t i; } v; v.f = f;
    uint32_t r = v.i + 0x7FFFu + ((v.i >> 16) & 1u);
    return (u16)(r >> 16);
}
__device__ __forceinline__ uint32_t pk2(float a, float b) {
    __hip_bfloat162 h = __float22bfloat162_rn(float2{a, b});
    return *(const uint32_t*)&h;
}
__device__ __forceinline__ uint4 pack8(float4 lo, float4 hi) {
    uint4 r;
    r.x = pk2(lo.x, lo.y); r.y = pk2(lo.z, lo.w);
    r.z = pk2(hi.x, hi.y); r.w = pk2(hi.z, hi.w);
    return r;
}
// async global->LDS DMA, 16B per lane (m97 idiom: LDS dst linear in lane)
__device__ __forceinline__ void async16(const u16* g, u16* l) {
    __builtin_amdgcn_global_load_lds(
        (const __attribute__((address_space(1))) uint32_t*)g,
        (__attribute__((address_space(3))) uint32_t*)l,
        16, 0, 0);
}

// ---------------- GEMM core: C[M,N] = X[M,1024] @ W[1024,N] + bias ----------------
// WT = W^T bf16 [N][K]. 128x128 tile, BK=64, 2x2 wave quadrants, 4x4 16x16x32 frags.
// LDS tiles 128x64, unpadded, XOR-swizzled: physical 16B-block pb of row r holds
// logical block pb^(r&7) -> frag b128 reads are 2-way (free). B staged via async16
// (zero VGPRs); A staged via transient f32->bf16 VGPR pass when XF32 (qkv) or
// async16 when bf16 (oproj). No registers held across the compute phase (R5 spill fix).
// mode 0: bf16 scatter [B,H,S,D]; mode 1: f32 row-major; mode 2: bf16 V^T [BH,64,2048]
template<bool XF32>
__device__ __forceinline__ void gemm128(const void* __restrict__ Xv,
                                        const u16* __restrict__ WT,
                                        const float* __restrict__ bias,
                                        u16* __restrict__ dstb,
                                        float* __restrict__ dstf, int mode)
{
    __shared__ __align__(16) u16 As[128 * 64];
    __shared__ __align__(16) u16 Bs[128 * 64];
    const int t    = threadIdx.x;
    const int lane = t & 63;
    const int quad = lane >> 4;
    const int l15  = lane & 15;
    const int m0 = blockIdx.y * 128;
    const int n0 = blockIdx.x * 128;
    const int wave = t >> 6;
    const int wm = (wave >> 1) * 64;
    const int wn = (wave & 1) * 64;

    f32x4 acc[4][4];
#pragma unroll
    for (int i = 0; i < 4; i++)
#pragma unroll
        for (int j = 0; j < 4; j++)
#pragma unroll
            for (int r = 0; r < 4; r++) acc[i][j][r] = 0.0f;

    // staging chunk map: ci = c*256+t; row r=ci>>3, physical block pb=ci&7,
    // logical (global) block lb = pb ^ (r&7)
    int rr[4], lb[4];
#pragma unroll
    for (int c = 0; c < 4; c++) {
        const int ci = c * 256 + t;
        rr[c] = ci >> 3;
        lb[c] = (ci & 7) ^ (rr[c] & 7);
    }

    for (int kt = 0; kt < 1024; kt += 64) {
        __syncthreads();                    // (a) prior tile's frag reads complete
#pragma unroll
        for (int c = 0; c < 4; c++)         // B: async DMA, no VGPRs
            async16(WT + (n0 + rr[c]) * 1024 + kt + lb[c] * 8, &Bs[(c * 256 + t) * 8]);
        if (XF32) {                         // A: f32 load -> bf16 pack -> LDS
#pragma unroll
            for (int c = 0; c < 4; c++) {
                const float* g = (const float*)Xv + (m0 + rr[c]) * 1024 + kt + lb[c] * 8;
                const float4 lo = *(const float4*)g;
                const float4 hi = *(const float4*)(g + 4);
                *(uint4*)&As[(c * 256 + t) * 8] = pack8(lo, hi);
            }
        } else {
#pragma unroll
            for (int c = 0; c < 4; c++)
                async16((const u16*)Xv + (m0 + rr[c]) * 1024 + kt + lb[c] * 8,
                        &As[(c * 256 + t) * 8]);
        }
        __syncthreads();                    // (b) vmcnt drained + staging visible

#pragma unroll
        for (int kk = 0; kk < 64; kk += 32) {
            bf16x8 af[4], bfv[4];
#pragma unroll
            for (int i = 0; i < 4; i++) {
                const int ra = wm + i * 16 + l15;
                const int rb2 = wn + i * 16 + l15;
                af[i]  = *(const bf16x8*)&As[ra * 64 + (((kk >> 3) + quad) ^ (l15 & 7)) * 8];
                bfv[i] = *(const bf16x8*)&Bs[rb2 * 64 + (((kk >> 3) + quad) ^ (l15 & 7)) * 8];
            }
#pragma unroll
            for (int i = 0; i < 4; i++)
#pragma unroll
                for (int j = 0; j < 4; j++)
                    acc[i][j] = __builtin_amdgcn_mfma_f32_16x16x32_bf16(af[i], bfv[j], acc[i][j], 0, 0, 0);
        }
    }

    // epilogue: C row = quad*4 + r, col = lane&15 (HW-verified R4)
#pragma unroll
    for (int i = 0; i < 4; i++) {
        const int rb = m0 + wm + i * 16 + quad * 4;
#pragma unroll
        for (int j = 0; j < 4; j++) {
            const int col = n0 + wn + j * 16 + l15;
            const float bias_v = bias[col];
            if (mode == 2) {
                // V^T direct store: 4 consecutive s at fixed (h,d) -> packed b64
                const int b = rb >> 11, s = rb & 2047;
                const int h = col >> 6, d = col & 63;
                uint2 pk;
                pk.x = pk2(acc[i][j][0] + bias_v, acc[i][j][1] + bias_v);
                pk.y = pk2(acc[i][j][2] + bias_v, acc[i][j][3] + bias_v);
                *(uint2*)&dstb[((b * 16 + h) * 64 + d) * 2048 + s] = pk;
            } else {
#pragma unroll
                for (int r = 0; r < 4; r++) {
                    const float v = acc[i][j][r] + bias_v;
                    const int gm = rb + r;
                    if (mode == 0) {
                        const int b = gm >> 11, s = gm & 2047;
                        const int h = col >> 6, d = col & 63;
                        dstb[((b * 16 + h) * 2048 + s) * 64 + d] = f2b(v);
                    } else {
                        dstf[gm * 1024 + col] = v;
                    }
                }
            }
        }
    }
}

__global__ __launch_bounds__(256)
void qkv_kernel(const float* __restrict__ q_in, const float* __restrict__ k_in,
                const float* __restrict__ v_in, const u16* __restrict__ WT,
                const float* __restrict__ bq, const float* __restrict__ bk,
                const float* __restrict__ bv,
                u16* __restrict__ Qo, u16* __restrict__ Ko, u16* __restrict__ VTo)
{
    const int z = blockIdx.z;
    const float* X   = (z == 0) ? q_in : (z == 1) ? k_in : v_in;
    const u16* wt    = WT + ((z == 0) ? 2 : (z == 1) ? 1 : 0) * (1024 * 1024);
    const float* bias= (z == 0) ? bq : (z == 1) ? bk : bv;
    u16* dst         = (z == 0) ? Qo : (z == 1) ? Ko : VTo;
    gemm128<true>(X, wt, bias, dst, nullptr, (z == 2) ? 2 : 0);
}

__global__ __launch_bounds__(256)
void oproj_kernel(const u16* __restrict__ AO, const u16* __restrict__ WT,
                  const float* __restrict__ bo, float* __restrict__ out)
{
    gemm128<false>(AO, WT + 3 * 1024 * 1024, bo, nullptr, out, 1);
}

// ---------------- weight transpose+cvt: W[1024 k][1024 n] f32 -> WT[n][k] bf16 ----
__global__ void transpose_w(const float* __restrict__ Wv, const float* __restrict__ Wk,
                            const float* __restrict__ Wq, const float* __restrict__ Wo,
                            u16* __restrict__ WT)
{
    __shared__ u16 tile[64][65];
    const int z = blockIdx.z;
    const float* W = (z == 0) ? Wv : (z == 1) ? Wk : (z == 2) ? Wq : Wo;
    u16* dst = WT + z * 1024 * 1024;
    const int r0 = blockIdx.y * 64, c0 = blockIdx.x * 64;
    const int col = threadIdx.x & 63, rb = threadIdx.x >> 6;
#pragma unroll
    for (int r = rb; r < 64; r += 4) tile[r][col] = f2b(W[(r0 + r) * 1024 + c0 + col]);
    __syncthreads();
#pragma unroll
    for (int r = rb; r < 64; r += 4) dst[(c0 + r) * 1024 + r0 + col] = tile[col][r];
}

// ---------------- flash attention (transposed): Tq=64/block, Tk=128 KV tiles -------
// S^T = K·Q^T -> per-lane online softmax (lane owns one q-row, 2 shuffles).
// K/V staged via async16 into unpadded XOR-swizzled LDS (no prefetch regs -> no
// spill). O^T = V^T·P^T.
// R6: Q lives in 8 VGPRs/lane -> Qs LDS eliminated.
// R7: Ps ALIASES Ks (phase-disjoint), barrier (c) orders last Ks read vs Ps write.
//     LDS 49152->32768 -> 5 blocks/CU possible.
// R8: launch_bounds min-waves 5->4. R7's (256,5) squeezed VGPR to 48 and spilled
//     the s[8]/o[4] accumulators to scratch (FETCH +66MB, WRITE +66MB, attn
//     163->237us). Natural allocation is ~80 VGPR (R6) -> cap 128 is spill-free
//     and still lets the LDS limit (5 blocks/CU) bind.
__global__ __launch_bounds__(256, 4)
void attn_kernel(const u16* __restrict__ Q, const u16* __restrict__ K,
                 const u16* __restrict__ VT, u16* __restrict__ AO)
{
    __shared__ __align__(16) u16 KPs[128 * 64];   // Ks (swizzle r&7) / Ps (swizzle r&15)
    __shared__ __align__(16) u16 Vts[64 * 128];   // swizzle r&15

    const int t    = threadIdx.x;
    const int lane = t & 63;
    const int wave = t >> 6;
    const int quad = lane >> 4;
    const int l15  = lane & 15;
    const int bh = blockIdx.y;
    const int qt = blockIdx.x;

    const u16* Qg = Q + (bh * 2048 + qt * 64) * 64;
    const u16* Kg = K + bh * 2048 * 64;
    const u16* Vg = VT + bh * 64 * 2048;

    // Q fragments in registers: lane needs row (wave*16+l15), cols quad*8 + {0..7}
    // at kk=0 and kk=32; fold 0.125*log2(e) so softmax runs in exp2 domain.
    bf16x8 bqr[2];
    {
        const u16* qrow = Qg + (wave * 16 + l15) * 64 + quad * 8;
#pragma unroll
        for (int c = 0; c < 2; c++) {
            uint4 dv = *(const uint4*)(qrow + c * 32);
            u16 tmp[8];
            *(uint4*)tmp = dv;
            float f[8];
#pragma unroll
            for (int i = 0; i < 8; i++) {
                union { float f; uint32_t u; } x; x.u = ((uint32_t)tmp[i]) << 16;
                f[i] = x.f * 0.18033688f;   // 0.125 * log2e
            }
            uint4 pk;
            pk.x = pk2(f[0], f[1]); pk.y = pk2(f[2], f[3]);
            pk.z = pk2(f[4], f[5]); pk.w = pk2(f[6], f[7]);
            bqr[c] = *(bf16x8*)&pk;
        }
    }

    f32x4 o[4];
#pragma unroll
    for (int dj = 0; dj < 4; dj++)
#pragma unroll
        for (int r = 0; r < 4; r++) o[dj][r] = 0.0f;
    float m_st = -1.0e30f, l_st = 0.0f;

    // staging maps (linear LDS chunk ci = c*256+t)
    int krr[4], klb[4], vrr[4], vlb[4];
#pragma unroll
    for (int c = 0; c < 4; c++) {
        const int ci = c * 256 + t;
        krr[c] = ci >> 3;  klb[c] = (ci & 7)  ^ (krr[c] & 7);
        vrr[c] = ci >> 4;  vlb[c] = (ci & 15) ^ (vrr[c] & 15);
    }

    for (int kv = 0; kv < 16; kv++) {
        const int j0 = kv * 128;
        __syncthreads();   // (a) prev tile's PV reads (KPs-as-Ps, Vts) done
#pragma unroll
        for (int c = 0; c < 4; c++) {
            async16(Kg + (j0 + krr[c]) * 64 + klb[c] * 8, &KPs[(c * 256 + t) * 8]);
            async16(Vg + vrr[c] * 2048 + j0 + vlb[c] * 8, &Vts[(c * 256 + t) * 8]);
        }
        __syncthreads();   // (b) DMA drained (vmcnt 0 before barrier) + visible

        // S^T = K·Q^T : A-frags = K rows (kv), B-frag = this wave's q-rows (regs)
        f32x4 s[8];
#pragma unroll
        for (int n = 0; n < 8; n++)
#pragma unroll
            for (int r = 0; r < 4; r++) s[n][r] = 0.0f;
#pragma unroll
        for (int kk = 0; kk < 64; kk += 32) {
            const bf16x8 bq = bqr[kk >> 5];
#pragma unroll
            for (int n = 0; n < 8; n++) {
                const bf16x8 ak = *(const bf16x8*)
                    &KPs[(n * 16 + l15) * 64 + (((kk >> 3) + quad) ^ (l15 & 7)) * 8];
                s[n] = __builtin_amdgcn_mfma_f32_16x16x32_bf16(ak, bq, s[n], 0, 0, 0);
            }
        }
        __syncthreads();   // (c) ALL waves' Ks reads done before Ps overwrites KPs

        // per-lane online softmax (q-row = l15 of this wave's 16); max3 trees
        float mxn[8];
#pragma unroll
        for (int n = 0; n < 8; n++)
            mxn[n] = fmaxf(fmaxf(s[n][0], s[n][1]), fmaxf(s[n][2], s[n][3]));
        float mx = fmaxf(fmaxf(fmaxf(mxn[0], mxn[1]), fmaxf(mxn[2], mxn[3])),
                         fmaxf(fmaxf(mxn[4], mxn[5]), fmaxf(mxn[6], mxn[7])));
        mx = fmaxf(mx, __shfl_xor(mx, 16));
        mx = fmaxf(mx, __shfl_xor(mx, 32));
        const float mnew = fmaxf(m_st, mx);
        const float alpha = exp2f(m_st - mnew);
        m_st = mnew;
        float sum = 0.0f;
#pragma unroll
        for (int n = 0; n < 8; n++)
#pragma unroll
            for (int r = 0; r < 4; r++) {
                const float p = exp2f(s[n][r] - m_st);
                s[n][r] = p;
                sum += p;
            }
        sum += __shfl_xor(sum, 16);
        sum += __shfl_xor(sum, 32);
        l_st = l_st * alpha + sum;
#pragma unroll
        for (int dj = 0; dj < 4; dj++)
#pragma unroll
            for (int r = 0; r < 4; r++) o[dj][r] *= alpha;

        // P^T[qrow][kv] -> swizzled LDS (aliasing Ks), packed b64
#pragma unroll
        for (int n = 0; n < 8; n++) {
            const int pbw = ((2 * n + (quad >> 1)) ^ l15);
            uint2 pk;
            pk.x = pk2(s[n][0], s[n][1]);
            pk.y = pk2(s[n][2], s[n][3]);
            *(uint2*)&KPs[(wave * 16 + l15) * 128 + pbw * 8 + (quad & 1) * 4] = pk;
        }
        asm volatile("s_waitcnt lgkmcnt(0)" ::: "memory");  // wave-private RAW fence

        // O^T += V^T·P^T
#pragma unroll
        for (int ks = 0; ks < 4; ks++) {
#pragma unroll
            for (int dj = 0; dj < 4; dj++) {
                const bf16x8 av = *(const bf16x8*)
                    &Vts[(dj * 16 + l15) * 128 + ((ks * 4 + quad) ^ l15) * 8];
                const bf16x8 bp = *(const bf16x8*)
                    &KPs[(wave * 16 + l15) * 128 + ((ks * 4 + quad) ^ l15) * 8];
                o[dj] = __builtin_amdgcn_mfma_f32_16x16x32_bf16(av, bp, o[dj], 0, 0, 0);
            }
        }
    }

    // epilogue: O^T[d = dj*16+quad*4+r][qrow = l15]; write bf16 [B,S,E] packed b64
    const int b = bh >> 4, h = bh & 15;
    const int sq = qt * 64 + wave * 16 + l15;
    const float inv = 1.0f / l_st;
#pragma unroll
    for (int dj = 0; dj < 4; dj++) {
        uint2 pk;
        pk.x = pk2(o[dj][0] * inv, o[dj][1] * inv);
        pk.y = pk2(o[dj][2] * inv, o[dj][3] * inv);
        *(uint2*)&AO[(b * 2048 + sq) * 1024 + h * 64 + dj * 16 + quad * 4] = pk;
    }
}

extern "C" void kernel_launch(void* const* d_in, const int* in_sizes, int n_in,
                              void* d_out, int out_size, void* d_ws, size_t ws_size,
                              hipStream_t stream)
{
    (void)in_sizes; (void)n_in; (void)out_size; (void)ws_size;
    const float* value = (const float*)d_in[0];
    const float* key_  = (const float*)d_in[1];
    const float* query = (const float*)d_in[2];
    const float* Wv = (const float*)d_in[3];
    const float* bv = (const float*)d_in[4];
    const float* Wk = (const float*)d_in[5];
    const float* bk = (const float*)d_in[6];
    const float* Wq = (const float*)d_in[7];
    const float* bq = (const float*)d_in[8];
    const float* Wo = (const float*)d_in[9];
    const float* bo = (const float*)d_in[10];

    u16* ws = (u16*)d_ws;
    u16* WT = ws;                          // 4 x 1M bf16 (order: v,k,q,o)
    u16* Q  = ws + 4 * 1024 * 1024;        // 8M bf16 [B,H,S,D]
    u16* K  = Q + 8 * 1024 * 1024;         // 8M [B,H,S,D]
    u16* VT = K + 8 * 1024 * 1024;         // 8M [B,H,D,S] (written directly by qkv)
    u16* AO = VT + 8 * 1024 * 1024;        // 8M [B*S, E]   (total 72 MB, proven)

    transpose_w<<<dim3(16, 16, 4), dim3(256), 0, stream>>>(Wv, Wk, Wq, Wo, WT);
    qkv_kernel<<<dim3(8, 64, 3), dim3(256), 0, stream>>>(query, key_, value, WT,
                                                         bq, bk, bv, Q, K, VT);
    attn_kernel<<<dim3(32, 64), dim3(256), 0, stream>>>(Q, K, VT, AO);
    oproj_kernel<<<dim3(8, 64, 1), dim3(256), 0, stream>>>(AO, WT, bo, (float*)d_out);
}

// Round 4
// 415.993 us; speedup vs baseline: 1.2039x; 1.0271x over previous
//
#include <hip/hip_runtime.h>
#include <hip/hip_bf16.h>
#include <stdint.h>

typedef unsigned short u16;
typedef __bf16 bf16_t;
typedef bf16_t bf16x8 __attribute__((ext_vector_type(8)));
typedef float f32x4 __attribute__((ext_vector_type(4)));

__device__ __forceinline__ u16 f2b(float f) {
    union { float f; uint32_t i; } v; v.f = f;
    uint32_t r = v.i + 0x7FFFu + ((v.i >> 16) & 1u);
    return (u16)(r >> 16);
}
__device__ __forceinline__ uint32_t pk2(float a, float b) {
    __hip_bfloat162 h = __float22bfloat162_rn(float2{a, b});
    return *(const uint32_t*)&h;
}
__device__ __forceinline__ uint4 pack8(float4 lo, float4 hi) {
    uint4 r;
    r.x = pk2(lo.x, lo.y); r.y = pk2(lo.z, lo.w);
    r.z = pk2(hi.x, hi.y); r.w = pk2(hi.z, hi.w);
    return r;
}
// async global->LDS DMA, 16B per lane (m97 idiom: LDS dst linear in lane)
__device__ __forceinline__ void async16(const u16* g, u16* l) {
    __builtin_amdgcn_global_load_lds(
        (const __attribute__((address_space(1))) uint32_t*)g,
        (__attribute__((address_space(3))) uint32_t*)l,
        16, 0, 0);
}

// ---------------- GEMM core: C[M,N] = X[M,1024] @ W[1024,N] + bias ----------------
// WT = W^T bf16 [N][K]. 128x128 tile, BK=64, 2x2 wave quadrants, 4x4 16x16x32 frags.
// LDS tiles 128x64, unpadded, XOR-swizzled: physical 16B-block pb of row r holds
// logical block pb^(r&7) -> frag b128 reads are 2-way (free). B staged via async16
// (zero VGPRs); A staged via transient f32->bf16 VGPR pass when XF32 (qkv fallback)
// or async16 when bf16. No registers held across the compute phase (R5 spill fix).
// mode 0: bf16 scatter [B,H,S,D]; mode 1: f32 row-major; mode 2: bf16 V^T [BH,64,2048]
template<bool XF32>
__device__ __forceinline__ void gemm128(const void* __restrict__ Xv,
                                        const u16* __restrict__ WT,
                                        const float* __restrict__ bias,
                                        u16* __restrict__ dstb,
                                        float* __restrict__ dstf, int mode)
{
    __shared__ __align__(16) u16 As[128 * 64];
    __shared__ __align__(16) u16 Bs[128 * 64];
    const int t    = threadIdx.x;
    const int lane = t & 63;
    const int quad = lane >> 4;
    const int l15  = lane & 15;
    const int m0 = blockIdx.y * 128;
    const int n0 = blockIdx.x * 128;
    const int wave = t >> 6;
    const int wm = (wave >> 1) * 64;
    const int wn = (wave & 1) * 64;

    f32x4 acc[4][4];
#pragma unroll
    for (int i = 0; i < 4; i++)
#pragma unroll
        for (int j = 0; j < 4; j++)
#pragma unroll
            for (int r = 0; r < 4; r++) acc[i][j][r] = 0.0f;

    // staging chunk map: ci = c*256+t; row r=ci>>3, physical block pb=ci&7,
    // logical (global) block lb = pb ^ (r&7)
    int rr[4], lb[4];
#pragma unroll
    for (int c = 0; c < 4; c++) {
        const int ci = c * 256 + t;
        rr[c] = ci >> 3;
        lb[c] = (ci & 7) ^ (rr[c] & 7);
    }

    for (int kt = 0; kt < 1024; kt += 64) {
        __syncthreads();                    // (a) prior tile's frag reads complete
#pragma unroll
        for (int c = 0; c < 4; c++)         // B: async DMA, no VGPRs
            async16(WT + (n0 + rr[c]) * 1024 + kt + lb[c] * 8, &Bs[(c * 256 + t) * 8]);
        if (XF32) {                         // A: f32 load -> bf16 pack -> LDS
#pragma unroll
            for (int c = 0; c < 4; c++) {
                const float* g = (const float*)Xv + (m0 + rr[c]) * 1024 + kt + lb[c] * 8;
                const float4 lo = *(const float4*)g;
                const float4 hi = *(const float4*)(g + 4);
                *(uint4*)&As[(c * 256 + t) * 8] = pack8(lo, hi);
            }
        } else {                            // A: async DMA (R9: bf16 prepass path)
#pragma unroll
            for (int c = 0; c < 4; c++)
                async16((const u16*)Xv + (m0 + rr[c]) * 1024 + kt + lb[c] * 8,
                        &As[(c * 256 + t) * 8]);
        }
        __syncthreads();                    // (b) vmcnt drained + staging visible

#pragma unroll
        for (int kk = 0; kk < 64; kk += 32) {
            bf16x8 af[4], bfv[4];
#pragma unroll
            for (int i = 0; i < 4; i++) {
                const int ra = wm + i * 16 + l15;
                const int rb2 = wn + i * 16 + l15;
                af[i]  = *(const bf16x8*)&As[ra * 64 + (((kk >> 3) + quad) ^ (l15 & 7)) * 8];
                bfv[i] = *(const bf16x8*)&Bs[rb2 * 64 + (((kk >> 3) + quad) ^ (l15 & 7)) * 8];
            }
#pragma unroll
            for (int i = 0; i < 4; i++)
#pragma unroll
                for (int j = 0; j < 4; j++)
                    acc[i][j] = __builtin_amdgcn_mfma_f32_16x16x32_bf16(af[i], bfv[j], acc[i][j], 0, 0, 0);
        }
    }

    // epilogue: C row = quad*4 + r, col = lane&15 (HW-verified R4)
#pragma unroll
    for (int i = 0; i < 4; i++) {
        const int rb = m0 + wm + i * 16 + quad * 4;
#pragma unroll
        for (int j = 0; j < 4; j++) {
            const int col = n0 + wn + j * 16 + l15;
            const float bias_v = bias[col];
            if (mode == 2) {
                // V^T direct store: 4 consecutive s at fixed (h,d) -> packed b64
                const int b = rb >> 11, s = rb & 2047;
                const int h = col >> 6, d = col & 63;
                uint2 pk;
                pk.x = pk2(acc[i][j][0] + bias_v, acc[i][j][1] + bias_v);
                pk.y = pk2(acc[i][j][2] + bias_v, acc[i][j][3] + bias_v);
                *(uint2*)&dstb[((b * 16 + h) * 64 + d) * 2048 + s] = pk;
            } else {
#pragma unroll
                for (int r = 0; r < 4; r++) {
                    const float v = acc[i][j][r] + bias_v;
                    const int gm = rb + r;
                    if (mode == 0) {
                        const int b = gm >> 11, s = gm & 2047;
                        const int h = col >> 6, d = col & 63;
                        dstb[((b * 16 + h) * 2048 + s) * 64 + d] = f2b(v);
                    } else {
                        dstf[gm * 1024 + col] = v;
                    }
                }
            }
        }
    }
}

// R9: f32 -> bf16 convert prepass (memory-bound, ~150 MB total traffic).
// Removes the VALU pack + ds_write from qkv's staging loop (m97 regime fix).
__global__ __launch_bounds__(256)
void convert_x(const float* __restrict__ q_in, const float* __restrict__ k_in,
               const float* __restrict__ v_in, u16* __restrict__ Xb)
{
    const int z = blockIdx.y;
    const float* src = (z == 0) ? q_in : (z == 1) ? k_in : v_in;
    u16* dst = Xb + z * (8 * 1024 * 1024);
    const int i = (blockIdx.x * 256 + threadIdx.x) * 8;
    const float4 lo = *(const float4*)(src + i);
    const float4 hi = *(const float4*)(src + i + 4);
    *(uint4*)(dst + i) = pack8(lo, hi);
}

__global__ __launch_bounds__(256)
void qkv_kernel_f32(const float* __restrict__ q_in, const float* __restrict__ k_in,
                    const float* __restrict__ v_in, const u16* __restrict__ WT,
                    const float* __restrict__ bq, const float* __restrict__ bk,
                    const float* __restrict__ bv,
                    u16* __restrict__ Qo, u16* __restrict__ Ko, u16* __restrict__ VTo)
{
    const int z = blockIdx.z;
    const float* X   = (z == 0) ? q_in : (z == 1) ? k_in : v_in;
    const u16* wt    = WT + ((z == 0) ? 2 : (z == 1) ? 1 : 0) * (1024 * 1024);
    const float* bias= (z == 0) ? bq : (z == 1) ? bk : bv;
    u16* dst         = (z == 0) ? Qo : (z == 1) ? Ko : VTo;
    gemm128<true>(X, wt, bias, dst, nullptr, (z == 2) ? 2 : 0);
}

// R9: all-async16 qkv reading pre-converted bf16 X
__global__ __launch_bounds__(256)
void qkv_kernel_b16(const u16* __restrict__ Xb, const u16* __restrict__ WT,
                    const float* __restrict__ bq, const float* __restrict__ bk,
                    const float* __restrict__ bv,
                    u16* __restrict__ Qo, u16* __restrict__ Ko, u16* __restrict__ VTo)
{
    const int z = blockIdx.z;
    const u16* X     = Xb + z * (8 * 1024 * 1024);
    const u16* wt    = WT + ((z == 0) ? 2 : (z == 1) ? 1 : 0) * (1024 * 1024);
    const float* bias= (z == 0) ? bq : (z == 1) ? bk : bv;
    u16* dst         = (z == 0) ? Qo : (z == 1) ? Ko : VTo;
    gemm128<false>(X, wt, bias, dst, nullptr, (z == 2) ? 2 : 0);
}

__global__ __launch_bounds__(256)
void oproj_kernel(const u16* __restrict__ AO, const u16* __restrict__ WT,
                  const float* __restrict__ bo, float* __restrict__ out)
{
    gemm128<false>(AO, WT + 3 * 1024 * 1024, bo, nullptr, out, 1);
}

// ---------------- weight transpose+cvt: W[1024 k][1024 n] f32 -> WT[n][k] bf16 ----
__global__ void transpose_w(const float* __restrict__ Wv, const float* __restrict__ Wk,
                            const float* __restrict__ Wq, const float* __restrict__ Wo,
                            u16* __restrict__ WT)
{
    __shared__ u16 tile[64][65];
    const int z = blockIdx.z;
    const float* W = (z == 0) ? Wv : (z == 1) ? Wk : (z == 2) ? Wq : Wo;
    u16* dst = WT + z * 1024 * 1024;
    const int r0 = blockIdx.y * 64, c0 = blockIdx.x * 64;
    const int col = threadIdx.x & 63, rb = threadIdx.x >> 6;
#pragma unroll
    for (int r = rb; r < 64; r += 4) tile[r][col] = f2b(W[(r0 + r) * 1024 + c0 + col]);
    __syncthreads();
#pragma unroll
    for (int r = rb; r < 64; r += 4) dst[(c0 + r) * 1024 + r0 + col] = tile[col][r];
}

// ---------------- flash attention (transposed): Tq=64/block, Tk=128 KV tiles -------
// S^T = K·Q^T -> per-lane online softmax (lane owns one q-row, 2 shuffles).
// K/V staged via async16 into unpadded XOR-swizzled LDS (no prefetch regs -> no
// spill). O^T = V^T·P^T.
// R6: Q lives in 8 VGPRs/lane -> Qs LDS eliminated.
// R7: Ps ALIASES Ks (phase-disjoint), barrier (c) orders last Ks read vs Ps write.
// R8: launch_bounds (256,4): (256,5) spilled (VGPR 48, +132MB scratch traffic);
//     at 64 VGPR no spill, occupancy 38%, attn 165us (VALU-floor regime).
__global__ __launch_bounds__(256, 4)
void attn_kernel(const u16* __restrict__ Q, const u16* __restrict__ K,
                 const u16* __restrict__ VT, u16* __restrict__ AO)
{
    __shared__ __align__(16) u16 KPs[128 * 64];   // Ks (swizzle r&7) / Ps (swizzle r&15)
    __shared__ __align__(16) u16 Vts[64 * 128];   // swizzle r&15

    const int t    = threadIdx.x;
    const int lane = t & 63;
    const int wave = t >> 6;
    const int quad = lane >> 4;
    const int l15  = lane & 15;
    const int bh = blockIdx.y;
    const int qt = blockIdx.x;

    const u16* Qg = Q + (bh * 2048 + qt * 64) * 64;
    const u16* Kg = K + bh * 2048 * 64;
    const u16* Vg = VT + bh * 64 * 2048;

    // Q fragments in registers: lane needs row (wave*16+l15), cols quad*8 + {0..7}
    // at kk=0 and kk=32; fold 0.125*log2(e) so softmax runs in exp2 domain.
    bf16x8 bqr[2];
    {
        const u16* qrow = Qg + (wave * 16 + l15) * 64 + quad * 8;
#pragma unroll
        for (int c = 0; c < 2; c++) {
            uint4 dv = *(const uint4*)(qrow + c * 32);
            u16 tmp[8];
            *(uint4*)tmp = dv;
            float f[8];
#pragma unroll
            for (int i = 0; i < 8; i++) {
                union { float f; uint32_t u; } x; x.u = ((uint32_t)tmp[i]) << 16;
                f[i] = x.f * 0.18033688f;   // 0.125 * log2e
            }
            uint4 pk;
            pk.x = pk2(f[0], f[1]); pk.y = pk2(f[2], f[3]);
            pk.z = pk2(f[4], f[5]); pk.w = pk2(f[6], f[7]);
            bqr[c] = *(bf16x8*)&pk;
        }
    }

    f32x4 o[4];
#pragma unroll
    for (int dj = 0; dj < 4; dj++)
#pragma unroll
        for (int r = 0; r < 4; r++) o[dj][r] = 0.0f;
    float m_st = -1.0e30f, l_st = 0.0f;

    // staging maps (linear LDS chunk ci = c*256+t)
    int krr[4], klb[4], vrr[4], vlb[4];
#pragma unroll
    for (int c = 0; c < 4; c++) {
        const int ci = c * 256 + t;
        krr[c] = ci >> 3;  klb[c] = (ci & 7)  ^ (krr[c] & 7);
        vrr[c] = ci >> 4;  vlb[c] = (ci & 15) ^ (vrr[c] & 15);
    }

    for (int kv = 0; kv < 16; kv++) {
        const int j0 = kv * 128;
        __syncthreads();   // (a) prev tile's PV reads (KPs-as-Ps, Vts) done
#pragma unroll
        for (int c = 0; c < 4; c++) {
            async16(Kg + (j0 + krr[c]) * 64 + klb[c] * 8, &KPs[(c * 256 + t) * 8]);
            async16(Vg + vrr[c] * 2048 + j0 + vlb[c] * 8, &Vts[(c * 256 + t) * 8]);
        }
        __syncthreads();   // (b) DMA drained (vmcnt 0 before barrier) + visible

        // S^T = K·Q^T : A-frags = K rows (kv), B-frag = this wave's q-rows (regs)
        f32x4 s[8];
#pragma unroll
        for (int n = 0; n < 8; n++)
#pragma unroll
            for (int r = 0; r < 4; r++) s[n][r] = 0.0f;
#pragma unroll
        for (int kk = 0; kk < 64; kk += 32) {
            const bf16x8 bq = bqr[kk >> 5];
#pragma unroll
            for (int n = 0; n < 8; n++) {
                const bf16x8 ak = *(const bf16x8*)
                    &KPs[(n * 16 + l15) * 64 + (((kk >> 3) + quad) ^ (l15 & 7)) * 8];
                s[n] = __builtin_amdgcn_mfma_f32_16x16x32_bf16(ak, bq, s[n], 0, 0, 0);
            }
        }
        __syncthreads();   // (c) ALL waves' Ks reads done before Ps overwrites KPs

        // per-lane online softmax (q-row = l15 of this wave's 16); max3 trees
        float mxn[8];
#pragma unroll
        for (int n = 0; n < 8; n++)
            mxn[n] = fmaxf(fmaxf(s[n][0], s[n][1]), fmaxf(s[n][2], s[n][3]));
        float mx = fmaxf(fmaxf(fmaxf(mxn[0], mxn[1]), fmaxf(mxn[2], mxn[3])),
                         fmaxf(fmaxf(mxn[4], mxn[5]), fmaxf(mxn[6], mxn[7])));
        mx = fmaxf(mx, __shfl_xor(mx, 16));
        mx = fmaxf(mx, __shfl_xor(mx, 32));
        const float mnew = fmaxf(m_st, mx);
        const float alpha = exp2f(m_st - mnew);
        m_st = mnew;
        float sum = 0.0f;
#pragma unroll
        for (int n = 0; n < 8; n++)
#pragma unroll
            for (int r = 0; r < 4; r++) {
                const float p = exp2f(s[n][r] - m_st);
                s[n][r] = p;
                sum += p;
            }
        sum += __shfl_xor(sum, 16);
        sum += __shfl_xor(sum, 32);
        l_st = l_st * alpha + sum;
#pragma unroll
        for (int dj = 0; dj < 4; dj++)
#pragma unroll
            for (int r = 0; r < 4; r++) o[dj][r] *= alpha;

        // P^T[qrow][kv] -> swizzled LDS (aliasing Ks), packed b64
#pragma unroll
        for (int n = 0; n < 8; n++) {
            const int pbw = ((2 * n + (quad >> 1)) ^ l15);
            uint2 pk;
            pk.x = pk2(s[n][0], s[n][1]);
            pk.y = pk2(s[n][2], s[n][3]);
            *(uint2*)&KPs[(wave * 16 + l15) * 128 + pbw * 8 + (quad & 1) * 4] = pk;
        }
        asm volatile("s_waitcnt lgkmcnt(0)" ::: "memory");  // wave-private RAW fence

        // O^T += V^T·P^T
#pragma unroll
        for (int ks = 0; ks < 4; ks++) {
#pragma unroll
            for (int dj = 0; dj < 4; dj++) {
                const bf16x8 av = *(const bf16x8*)
                    &Vts[(dj * 16 + l15) * 128 + ((ks * 4 + quad) ^ l15) * 8];
                const bf16x8 bp = *(const bf16x8*)
                    &KPs[(wave * 16 + l15) * 128 + ((ks * 4 + quad) ^ l15) * 8];
                o[dj] = __builtin_amdgcn_mfma_f32_16x16x32_bf16(av, bp, o[dj], 0, 0, 0);
            }
        }
    }

    // epilogue: O^T[d = dj*16+quad*4+r][qrow = l15]; write bf16 [B,S,E] packed b64
    const int b = bh >> 4, h = bh & 15;
    const int sq = qt * 64 + wave * 16 + l15;
    const float inv = 1.0f / l_st;
#pragma unroll
    for (int dj = 0; dj < 4; dj++) {
        uint2 pk;
        pk.x = pk2(o[dj][0] * inv, o[dj][1] * inv);
        pk.y = pk2(o[dj][2] * inv, o[dj][3] * inv);
        *(uint2*)&AO[(b * 2048 + sq) * 1024 + h * 64 + dj * 16 + quad * 4] = pk;
    }
}

extern "C" void kernel_launch(void* const* d_in, const int* in_sizes, int n_in,
                              void* d_out, int out_size, void* d_ws, size_t ws_size,
                              hipStream_t stream)
{
    (void)in_sizes; (void)n_in; (void)out_size;
    const float* value = (const float*)d_in[0];
    const float* key_  = (const float*)d_in[1];
    const float* query = (const float*)d_in[2];
    const float* Wv = (const float*)d_in[3];
    const float* bv = (const float*)d_in[4];
    const float* Wk = (const float*)d_in[5];
    const float* bk = (const float*)d_in[6];
    const float* Wq = (const float*)d_in[7];
    const float* bq = (const float*)d_in[8];
    const float* Wo = (const float*)d_in[9];
    const float* bo = (const float*)d_in[10];

    u16* ws = (u16*)d_ws;
    u16* WT = ws;                          // 4 x 1M bf16 (order: v,k,q,o)
    u16* Q  = ws + 4 * 1024 * 1024;        // 8M bf16 [B,H,S,D]
    u16* K  = Q + 8 * 1024 * 1024;         // 8M [B,H,S,D]
    u16* VT = K + 8 * 1024 * 1024;         // 8M [B,H,D,S] (written directly by qkv)
    u16* AO = VT + 8 * 1024 * 1024;        // 8M [B*S, E]   (72 MB so far)
    u16* Xb = AO + 8 * 1024 * 1024;        // 3 x 8M bf16 converted inputs (q,k,v)
    const size_t need = (size_t)(4 + 8 + 8 + 8 + 8 + 24) * 1024 * 1024 * sizeof(u16);

    transpose_w<<<dim3(16, 16, 4), dim3(256), 0, stream>>>(Wv, Wk, Wq, Wo, WT);
    if (ws_size >= need) {
        // R9 path: bf16 convert prepass, then all-async16 qkv staging
        convert_x<<<dim3(4096, 3), dim3(256), 0, stream>>>(query, key_, value, Xb);
        qkv_kernel_b16<<<dim3(8, 64, 3), dim3(256), 0, stream>>>(Xb, WT, bq, bk, bv,
                                                                 Q, K, VT);
    } else {
        qkv_kernel_f32<<<dim3(8, 64, 3), dim3(256), 0, stream>>>(query, key_, value,
                                                                 WT, bq, bk, bv,
                                                                 Q, K, VT);
    }
    attn_kernel<<<dim3(32, 64), dim3(256), 0, stream>>>(Q, K, VT, AO);
    oproj_kernel<<<dim3(8, 64, 1), dim3(256), 0, stream>>>(AO, WT, bo, (float*)d_out);
}

// Round 5
// 415.252 us; speedup vs baseline: 1.2060x; 1.0018x over previous
//
#include <hip/hip_runtime.h>
#include <hip/hip_bf16.h>
#include <stdint.h>

typedef unsigned short u16;
typedef __bf16 bf16_t;
typedef bf16_t bf16x8 __attribute__((ext_vector_type(8)));
typedef float f32x4 __attribute__((ext_vector_type(4)));

__device__ __forceinline__ u16 f2b(float f) {
    union { float f; uint32_t i; } v; v.f = f;
    uint32_t r = v.i + 0x7FFFu + ((v.i >> 16) & 1u);
    return (u16)(r >> 16);
}
__device__ __forceinline__ uint32_t pk2(float a, float b) {
    __hip_bfloat162 h = __float22bfloat162_rn(float2{a, b});
    return *(const uint32_t*)&h;
}
__device__ __forceinline__ uint4 pack8(float4 lo, float4 hi) {
    uint4 r;
    r.x = pk2(lo.x, lo.y); r.y = pk2(lo.z, lo.w);
    r.z = pk2(hi.x, hi.y); r.w = pk2(hi.z, hi.w);
    return r;
}
// async global->LDS DMA, 16B per lane (m97 idiom: LDS dst linear in lane)
__device__ __forceinline__ void async16(const u16* g, u16* l) {
    __builtin_amdgcn_global_load_lds(
        (const __attribute__((address_space(1))) uint32_t*)g,
        (__attribute__((address_space(3))) uint32_t*)l,
        16, 0, 0);
}

// ---------------- GEMM core: C[M,N] = X[M,1024] @ W[1024,N] + bias ----------------
// WT = W^T bf16 [N][K]. 128x128 tile, BK=64, 2x2 wave quadrants, 4x4 16x16x32 frags.
// LDS tiles 128x64, unpadded, XOR-swizzled: physical 16B-block pb of row r holds
// logical block pb^(r&7) -> frag b128 reads are 2-way (free). B staged via async16
// (zero VGPRs); A staged via transient f32->bf16 VGPR pass when XF32 (qkv fallback)
// or async16 when bf16. No registers held across the compute phase (R5 spill fix).
// mode 0: bf16 scatter [B,H,S,D]; mode 1: f32 row-major; mode 2: bf16 V^T [BH,64,2048]
template<bool XF32>
__device__ __forceinline__ void gemm128(const void* __restrict__ Xv,
                                        const u16* __restrict__ WT,
                                        const float* __restrict__ bias,
                                        u16* __restrict__ dstb,
                                        float* __restrict__ dstf, int mode)
{
    __shared__ __align__(16) u16 As[128 * 64];
    __shared__ __align__(16) u16 Bs[128 * 64];
    const int t    = threadIdx.x;
    const int lane = t & 63;
    const int quad = lane >> 4;
    const int l15  = lane & 15;
    const int m0 = blockIdx.y * 128;
    const int n0 = blockIdx.x * 128;
    const int wave = t >> 6;
    const int wm = (wave >> 1) * 64;
    const int wn = (wave & 1) * 64;

    f32x4 acc[4][4];
#pragma unroll
    for (int i = 0; i < 4; i++)
#pragma unroll
        for (int j = 0; j < 4; j++)
#pragma unroll
            for (int r = 0; r < 4; r++) acc[i][j][r] = 0.0f;

    // staging chunk map: ci = c*256+t; row r=ci>>3, physical block pb=ci&7,
    // logical (global) block lb = pb ^ (r&7)
    int rr[4], lb[4];
#pragma unroll
    for (int c = 0; c < 4; c++) {
        const int ci = c * 256 + t;
        rr[c] = ci >> 3;
        lb[c] = (ci & 7) ^ (rr[c] & 7);
    }

    for (int kt = 0; kt < 1024; kt += 64) {
        __syncthreads();                    // (a) prior tile's frag reads complete
#pragma unroll
        for (int c = 0; c < 4; c++)         // B: async DMA, no VGPRs
            async16(WT + (n0 + rr[c]) * 1024 + kt + lb[c] * 8, &Bs[(c * 256 + t) * 8]);
        if (XF32) {                         // A: f32 load -> bf16 pack -> LDS
#pragma unroll
            for (int c = 0; c < 4; c++) {
                const float* g = (const float*)Xv + (m0 + rr[c]) * 1024 + kt + lb[c] * 8;
                const float4 lo = *(const float4*)g;
                const float4 hi = *(const float4*)(g + 4);
                *(uint4*)&As[(c * 256 + t) * 8] = pack8(lo, hi);
            }
        } else {                            // A: async DMA (R9: bf16 prepass path)
#pragma unroll
            for (int c = 0; c < 4; c++)
                async16((const u16*)Xv + (m0 + rr[c]) * 1024 + kt + lb[c] * 8,
                        &As[(c * 256 + t) * 8]);
        }
        __syncthreads();                    // (b) vmcnt drained + staging visible

#pragma unroll
        for (int kk = 0; kk < 64; kk += 32) {
            bf16x8 af[4], bfv[4];
#pragma unroll
            for (int i = 0; i < 4; i++) {
                const int ra = wm + i * 16 + l15;
                const int rb2 = wn + i * 16 + l15;
                af[i]  = *(const bf16x8*)&As[ra * 64 + (((kk >> 3) + quad) ^ (l15 & 7)) * 8];
                bfv[i] = *(const bf16x8*)&Bs[rb2 * 64 + (((kk >> 3) + quad) ^ (l15 & 7)) * 8];
            }
#pragma unroll
            for (int i = 0; i < 4; i++)
#pragma unroll
                for (int j = 0; j < 4; j++)
                    acc[i][j] = __builtin_amdgcn_mfma_f32_16x16x32_bf16(af[i], bfv[j], acc[i][j], 0, 0, 0);
        }
    }

    // epilogue: C row = quad*4 + r, col = lane&15 (HW-verified R4)
#pragma unroll
    for (int i = 0; i < 4; i++) {
        const int rb = m0 + wm + i * 16 + quad * 4;
#pragma unroll
        for (int j = 0; j < 4; j++) {
            const int col = n0 + wn + j * 16 + l15;
            const float bias_v = bias[col];
            if (mode == 2) {
                // V^T direct store: 4 consecutive s at fixed (h,d) -> packed b64
                const int b = rb >> 11, s = rb & 2047;
                const int h = col >> 6, d = col & 63;
                uint2 pk;
                pk.x = pk2(acc[i][j][0] + bias_v, acc[i][j][1] + bias_v);
                pk.y = pk2(acc[i][j][2] + bias_v, acc[i][j][3] + bias_v);
                *(uint2*)&dstb[((b * 16 + h) * 64 + d) * 2048 + s] = pk;
            } else {
#pragma unroll
                for (int r = 0; r < 4; r++) {
                    const float v = acc[i][j][r] + bias_v;
                    const int gm = rb + r;
                    if (mode == 0) {
                        const int b = gm >> 11, s = gm & 2047;
                        const int h = col >> 6, d = col & 63;
                        dstb[((b * 16 + h) * 2048 + s) * 64 + d] = f2b(v);
                    } else {
                        dstf[gm * 1024 + col] = v;
                    }
                }
            }
        }
    }
}

// R9: f32 -> bf16 convert prepass (memory-bound, ~150 MB total traffic).
__global__ __launch_bounds__(256)
void convert_x(const float* __restrict__ q_in, const float* __restrict__ k_in,
               const float* __restrict__ v_in, u16* __restrict__ Xb)
{
    const int z = blockIdx.y;
    const float* src = (z == 0) ? q_in : (z == 1) ? k_in : v_in;
    u16* dst = Xb + z * (8 * 1024 * 1024);
    const int i = (blockIdx.x * 256 + threadIdx.x) * 8;
    const float4 lo = *(const float4*)(src + i);
    const float4 hi = *(const float4*)(src + i + 4);
    *(uint4*)(dst + i) = pack8(lo, hi);
}

__global__ __launch_bounds__(256)
void qkv_kernel_f32(const float* __restrict__ q_in, const float* __restrict__ k_in,
                    const float* __restrict__ v_in, const u16* __restrict__ WT,
                    const float* __restrict__ bq, const float* __restrict__ bk,
                    const float* __restrict__ bv,
                    u16* __restrict__ Qo, u16* __restrict__ Ko, u16* __restrict__ VTo)
{
    const int z = blockIdx.z;
    const float* X   = (z == 0) ? q_in : (z == 1) ? k_in : v_in;
    const u16* wt    = WT + ((z == 0) ? 2 : (z == 1) ? 1 : 0) * (1024 * 1024);
    const float* bias= (z == 0) ? bq : (z == 1) ? bk : bv;
    u16* dst         = (z == 0) ? Qo : (z == 1) ? Ko : VTo;
    gemm128<true>(X, wt, bias, dst, nullptr, (z == 2) ? 2 : 0);
}

// R9: all-async16 qkv reading pre-converted bf16 X
__global__ __launch_bounds__(256)
void qkv_kernel_b16(const u16* __restrict__ Xb, const u16* __restrict__ WT,
                    const float* __restrict__ bq, const float* __restrict__ bk,
                    const float* __restrict__ bv,
                    u16* __restrict__ Qo, u16* __restrict__ Ko, u16* __restrict__ VTo)
{
    const int z = blockIdx.z;
    const u16* X     = Xb + z * (8 * 1024 * 1024);
    const u16* wt    = WT + ((z == 0) ? 2 : (z == 1) ? 1 : 0) * (1024 * 1024);
    const float* bias= (z == 0) ? bq : (z == 1) ? bk : bv;
    u16* dst         = (z == 0) ? Qo : (z == 1) ? Ko : VTo;
    gemm128<false>(X, wt, bias, dst, nullptr, (z == 2) ? 2 : 0);
}

__global__ __launch_bounds__(256)
void oproj_kernel(const u16* __restrict__ AO, const u16* __restrict__ WT,
                  const float* __restrict__ bo, float* __restrict__ out)
{
    gemm128<false>(AO, WT + 3 * 1024 * 1024, bo, nullptr, out, 1);
}

// ---------------- weight transpose+cvt: W[1024 k][1024 n] f32 -> WT[n][k] bf16 ----
__global__ void transpose_w(const float* __restrict__ Wv, const float* __restrict__ Wk,
                            const float* __restrict__ Wq, const float* __restrict__ Wo,
                            u16* __restrict__ WT)
{
    __shared__ u16 tile[64][65];
    const int z = blockIdx.z;
    const float* W = (z == 0) ? Wv : (z == 1) ? Wk : (z == 2) ? Wq : Wo;
    u16* dst = WT + z * 1024 * 1024;
    const int r0 = blockIdx.y * 64, c0 = blockIdx.x * 64;
    const int col = threadIdx.x & 63, rb = threadIdx.x >> 6;
#pragma unroll
    for (int r = rb; r < 64; r += 4) tile[r][col] = f2b(W[(r0 + r) * 1024 + c0 + col]);
    __syncthreads();
#pragma unroll
    for (int r = rb; r < 64; r += 4) dst[(c0 + r) * 1024 + r0 + col] = tile[col][r];
}

// ---------------- flash attention (transposed): Tq=64/block, Tk=128 KV tiles -------
// S^T = K·Q^T -> per-lane online softmax (lane owns one q-row, 2 shuffles).
// K/V staged via async16 into unpadded XOR-swizzled LDS. O^T = V^T·P^T.
// R6: Q lives in 8 VGPRs/lane -> Qs LDS eliminated.
// R7: Ps ALIASES Ks (phase-disjoint), barrier (c) orders last Ks read vs Ps write.
// R8: (256,5) spilled (VGPR 48, +132MB scratch); (256,4) -> 64 VGPR, no spill.
// R10: 64 VGPR = allocator chasing the 8-wave bucket while LDS caps us at ~3
//      blocks/CU -> all ~44 loop-invariant swizzled LDS offsets + 8 global srcs
//      were rematerialized EVERY kv iter (VALUBusy 68.6 vs MfmaUtil 18.3).
//      Fix: launch_bounds (256,3) (cap 170 VGPR = the occupancy LDS allows) +
//      explicit source-level hoist of all invariant addresses (static arrays,
//      fully unrolled indexing -> stays in VGPRs, rule-#20 safe).
__global__ __launch_bounds__(256, 3)
void attn_kernel(const u16* __restrict__ Q, const u16* __restrict__ K,
                 const u16* __restrict__ VT, u16* __restrict__ AO)
{
    __shared__ __align__(16) u16 KPs[128 * 64];   // Ks (swizzle r&7) / Ps (swizzle r&15)
    __shared__ __align__(16) u16 Vts[64 * 128];   // swizzle r&15

    const int t    = threadIdx.x;
    const int lane = t & 63;
    const int wave = t >> 6;
    const int quad = lane >> 4;
    const int l15  = lane & 15;
    const int bh = blockIdx.y;
    const int qt = blockIdx.x;

    const u16* Qg = Q + (bh * 2048 + qt * 64) * 64;
    const u16* Kg = K + bh * 2048 * 64;
    const u16* Vg = VT + bh * 64 * 2048;

    // Q fragments in registers (fold 0.125*log2e -> exp2 domain)
    bf16x8 bqr[2];
    {
        const u16* qrow = Qg + (wave * 16 + l15) * 64 + quad * 8;
#pragma unroll
        for (int c = 0; c < 2; c++) {
            uint4 dv = *(const uint4*)(qrow + c * 32);
            u16 tmp[8];
            *(uint4*)tmp = dv;
            float f[8];
#pragma unroll
            for (int i = 0; i < 8; i++) {
                union { float f; uint32_t u; } x; x.u = ((uint32_t)tmp[i]) << 16;
                f[i] = x.f * 0.18033688f;   // 0.125 * log2e
            }
            uint4 pk;
            pk.x = pk2(f[0], f[1]); pk.y = pk2(f[2], f[3]);
            pk.z = pk2(f[4], f[5]); pk.w = pk2(f[6], f[7]);
            bqr[c] = *(bf16x8*)&pk;
        }
    }

    f32x4 o[4];
#pragma unroll
    for (int dj = 0; dj < 4; dj++)
#pragma unroll
        for (int r = 0; r < 4; r++) o[dj][r] = 0.0f;
    float m_st = -1.0e30f, l_st = 0.0f;

    // ---- R10: hoist ALL loop-invariant addresses (statically indexed) ----
    // staging: running global src pointers + fixed LDS dests
    const u16* kgp[4];
    const u16* vgp[4];
    u16* kld[4];
    u16* vld[4];
#pragma unroll
    for (int c = 0; c < 4; c++) {
        const int ci = c * 256 + t;
        const int krr = ci >> 3, klb = (ci & 7)  ^ (krr & 7);
        const int vrr = ci >> 4, vlb = (ci & 15) ^ (vrr & 15);
        kgp[c] = Kg + krr * 64 + klb * 8;      // += 128*64 per iter
        vgp[c] = Vg + vrr * 2048 + vlb * 8;    // += 128 per iter
        kld[c] = &KPs[ci * 8];
        vld[c] = &Vts[ci * 8];
    }
    // QK^T A-frag LDS offsets (u16 units): [kk/32][n]
    int ak_off[2][8];
#pragma unroll
    for (int ki = 0; ki < 2; ki++)
#pragma unroll
        for (int n = 0; n < 8; n++)
            ak_off[ki][n] = (n * 16 + l15) * 64 + (((ki * 4) + quad) ^ (l15 & 7)) * 8;
    // PV offsets: av [ks][dj], bp [ks]; P-write offsets pw [n]
    int av_off[4][4], bp_off[4], pw_off[8];
#pragma unroll
    for (int ks = 0; ks < 4; ks++) {
        bp_off[ks] = (wave * 16 + l15) * 128 + ((ks * 4 + quad) ^ l15) * 8;
#pragma unroll
        for (int dj = 0; dj < 4; dj++)
            av_off[ks][dj] = (dj * 16 + l15) * 128 + ((ks * 4 + quad) ^ l15) * 8;
    }
#pragma unroll
    for (int n = 0; n < 8; n++)
        pw_off[n] = (wave * 16 + l15) * 128 + ((2 * n + (quad >> 1)) ^ l15) * 8
                    + (quad & 1) * 4;

    for (int kv = 0; kv < 16; kv++) {
        __syncthreads();   // (a) prev tile's PV reads (KPs-as-Ps, Vts) done
#pragma unroll
        for (int c = 0; c < 4; c++) {
            async16(kgp[c], kld[c]);
            async16(vgp[c], vld[c]);
        }
        __syncthreads();   // (b) DMA drained (vmcnt 0 before barrier) + visible

        // S^T = K·Q^T
        f32x4 s[8];
#pragma unroll
        for (int n = 0; n < 8; n++)
#pragma unroll
            for (int r = 0; r < 4; r++) s[n][r] = 0.0f;
#pragma unroll
        for (int ki = 0; ki < 2; ki++) {
            const bf16x8 bq = bqr[ki];
#pragma unroll
            for (int n = 0; n < 8; n++) {
                const bf16x8 ak = *(const bf16x8*)&KPs[ak_off[ki][n]];
                s[n] = __builtin_amdgcn_mfma_f32_16x16x32_bf16(ak, bq, s[n], 0, 0, 0);
            }
        }
        __syncthreads();   // (c) ALL waves' Ks reads done before Ps overwrites KPs

        // per-lane online softmax; max3 trees
        float mxn[8];
#pragma unroll
        for (int n = 0; n < 8; n++)
            mxn[n] = fmaxf(fmaxf(s[n][0], s[n][1]), fmaxf(s[n][2], s[n][3]));
        float mx = fmaxf(fmaxf(fmaxf(mxn[0], mxn[1]), fmaxf(mxn[2], mxn[3])),
                         fmaxf(fmaxf(mxn[4], mxn[5]), fmaxf(mxn[6], mxn[7])));
        mx = fmaxf(mx, __shfl_xor(mx, 16));
        mx = fmaxf(mx, __shfl_xor(mx, 32));
        const float mnew = fmaxf(m_st, mx);
        const float alpha = exp2f(m_st - mnew);
        m_st = mnew;
        float sum = 0.0f;
#pragma unroll
        for (int n = 0; n < 8; n++)
#pragma unroll
            for (int r = 0; r < 4; r++) {
                const float p = exp2f(s[n][r] - m_st);
                s[n][r] = p;
                sum += p;
            }
        sum += __shfl_xor(sum, 16);
        sum += __shfl_xor(sum, 32);
        l_st = l_st * alpha + sum;
#pragma unroll
        for (int dj = 0; dj < 4; dj++)
#pragma unroll
            for (int r = 0; r < 4; r++) o[dj][r] *= alpha;

        // P^T -> swizzled LDS (aliasing Ks), packed b64
#pragma unroll
        for (int n = 0; n < 8; n++) {
            uint2 pk;
            pk.x = pk2(s[n][0], s[n][1]);
            pk.y = pk2(s[n][2], s[n][3]);
            *(uint2*)&KPs[pw_off[n]] = pk;
        }
        asm volatile("s_waitcnt lgkmcnt(0)" ::: "memory");  // wave-private RAW fence

        // O^T += V^T·P^T
#pragma unroll
        for (int ks = 0; ks < 4; ks++) {
            const bf16x8 bp = *(const bf16x8*)&KPs[bp_off[ks]];
#pragma unroll
            for (int dj = 0; dj < 4; dj++) {
                const bf16x8 av = *(const bf16x8*)&Vts[av_off[ks][dj]];
                o[dj] = __builtin_amdgcn_mfma_f32_16x16x32_bf16(av, bp, o[dj], 0, 0, 0);
            }
        }

#pragma unroll
        for (int c = 0; c < 4; c++) {
            kgp[c] += 128 * 64;
            vgp[c] += 128;
        }
    }

    // epilogue: O^T[d = dj*16+quad*4+r][qrow = l15]; write bf16 [B,S,E] packed b64
    const int b = bh >> 4, h = bh & 15;
    const int sq = qt * 64 + wave * 16 + l15;
    const float inv = 1.0f / l_st;
#pragma unroll
    for (int dj = 0; dj < 4; dj++) {
        uint2 pk;
        pk.x = pk2(o[dj][0] * inv, o[dj][1] * inv);
        pk.y = pk2(o[dj][2] * inv, o[dj][3] * inv);
        *(uint2*)&AO[(b * 2048 + sq) * 1024 + h * 64 + dj * 16 + quad * 4] = pk;
    }
}

extern "C" void kernel_launch(void* const* d_in, const int* in_sizes, int n_in,
                              void* d_out, int out_size, void* d_ws, size_t ws_size,
                              hipStream_t stream)
{
    (void)in_sizes; (void)n_in; (void)out_size;
    const float* value = (const float*)d_in[0];
    const float* key_  = (const float*)d_in[1];
    const float* query = (const float*)d_in[2];
    const float* Wv = (const float*)d_in[3];
    const float* bv = (const float*)d_in[4];
    const float* Wk = (const float*)d_in[5];
    const float* bk = (const float*)d_in[6];
    const float* Wq = (const float*)d_in[7];
    const float* bq = (const float*)d_in[8];
    const float* Wo = (const float*)d_in[9];
    const float* bo = (const float*)d_in[10];

    u16* ws = (u16*)d_ws;
    u16* WT = ws;                          // 4 x 1M bf16 (order: v,k,q,o)
    u16* Q  = ws + 4 * 1024 * 1024;        // 8M bf16 [B,H,S,D]
    u16* K  = Q + 8 * 1024 * 1024;         // 8M [B,H,S,D]
    u16* VT = K + 8 * 1024 * 1024;         // 8M [B,H,D,S] (written directly by qkv)
    u16* AO = VT + 8 * 1024 * 1024;        // 8M [B*S, E]   (72 MB so far)
    u16* Xb = AO + 8 * 1024 * 1024;        // 3 x 8M bf16 converted inputs (q,k,v)
    const size_t need = (size_t)(4 + 8 + 8 + 8 + 8 + 24) * 1024 * 1024 * sizeof(u16);

    transpose_w<<<dim3(16, 16, 4), dim3(256), 0, stream>>>(Wv, Wk, Wq, Wo, WT);
    if (ws_size >= need) {
        convert_x<<<dim3(4096, 3), dim3(256), 0, stream>>>(query, key_, value, Xb);
        qkv_kernel_b16<<<dim3(8, 64, 3), dim3(256), 0, stream>>>(Xb, WT, bq, bk, bv,
                                                                 Q, K, VT);
    } else {
        qkv_kernel_f32<<<dim3(8, 64, 3), dim3(256), 0, stream>>>(query, key_, value,
                                                                 WT, bq, bk, bv,
                                                                 Q, K, VT);
    }
    attn_kernel<<<dim3(32, 64), dim3(256), 0, stream>>>(Q, K, VT, AO);
    oproj_kernel<<<dim3(8, 64, 1), dim3(256), 0, stream>>>(AO, WT, bo, (float*)d_out);
}

// Round 6
// 391.664 us; speedup vs baseline: 1.2786x; 1.0602x over previous
//
#include <hip/hip_runtime.h>
#include <hip/hip_bf16.h>
#include <stdint.h>

typedef unsigned short u16;
typedef __bf16 bf16_t;
typedef bf16_t bf16x8 __attribute__((ext_vector_type(8)));
typedef float f32x4 __attribute__((ext_vector_type(4)));

__device__ __forceinline__ u16 f2b(float f) {
    union { float f; uint32_t i; } v; v.f = f;
    uint32_t r = v.i + 0x7FFFu + ((v.i >> 16) & 1u);
    return (u16)(r >> 16);
}
__device__ __forceinline__ uint32_t pk2(float a, float b) {
    __hip_bfloat162 h = __float22bfloat162_rn(float2{a, b});
    return *(const uint32_t*)&h;
}
__device__ __forceinline__ uint4 pack8(float4 lo, float4 hi) {
    uint4 r;
    r.x = pk2(lo.x, lo.y); r.y = pk2(lo.z, lo.w);
    r.z = pk2(hi.x, hi.y); r.w = pk2(hi.z, hi.w);
    return r;
}
// async global->LDS DMA, 16B per lane (m97 idiom: LDS dst linear in lane)
__device__ __forceinline__ void async16(const u16* g, u16* l) {
    __builtin_amdgcn_global_load_lds(
        (const __attribute__((address_space(1))) uint32_t*)g,
        (__attribute__((address_space(3))) uint32_t*)l,
        16, 0, 0);
}

// ---------------- GEMM core: C[M,N] = X[M,1024] @ W[1024,N] + bias ----------------
// WT = W^T bf16 [N][K]. 128x128 tile, BK=64, 2x2 wave quadrants, 4x4 16x16x32 frags.
// LDS tiles 128x64, unpadded, XOR-swizzled: physical 16B-block pb of row r holds
// logical block pb^(r&7) -> frag b128 reads are 2-way (free). B staged via async16
// (zero VGPRs); A staged via transient f32->bf16 VGPR pass when XF32 (qkv fallback)
// or async16 when bf16. No registers held across the compute phase (R5 spill fix).
// mode 0: bf16 scatter [B,H,S,D]; mode 1: f32 row-major; mode 2: bf16 V^T [BH,64,2048]
template<bool XF32>
__device__ __forceinline__ void gemm128(const void* __restrict__ Xv,
                                        const u16* __restrict__ WT,
                                        const float* __restrict__ bias,
                                        u16* __restrict__ dstb,
                                        float* __restrict__ dstf, int mode)
{
    __shared__ __align__(16) u16 As[128 * 64];
    __shared__ __align__(16) u16 Bs[128 * 64];
    const int t    = threadIdx.x;
    const int lane = t & 63;
    const int quad = lane >> 4;
    const int l15  = lane & 15;
    const int m0 = blockIdx.y * 128;
    const int n0 = blockIdx.x * 128;
    const int wave = t >> 6;
    const int wm = (wave >> 1) * 64;
    const int wn = (wave & 1) * 64;

    f32x4 acc[4][4];
#pragma unroll
    for (int i = 0; i < 4; i++)
#pragma unroll
        for (int j = 0; j < 4; j++)
#pragma unroll
            for (int r = 0; r < 4; r++) acc[i][j][r] = 0.0f;

    // staging chunk map: ci = c*256+t; row r=ci>>3, physical block pb=ci&7,
    // logical (global) block lb = pb ^ (r&7)
    int rr[4], lb[4];
#pragma unroll
    for (int c = 0; c < 4; c++) {
        const int ci = c * 256 + t;
        rr[c] = ci >> 3;
        lb[c] = (ci & 7) ^ (rr[c] & 7);
    }

    for (int kt = 0; kt < 1024; kt += 64) {
        __syncthreads();                    // (a) prior tile's frag reads complete
#pragma unroll
        for (int c = 0; c < 4; c++)         // B: async DMA, no VGPRs
            async16(WT + (n0 + rr[c]) * 1024 + kt + lb[c] * 8, &Bs[(c * 256 + t) * 8]);
        if (XF32) {                         // A: f32 load -> bf16 pack -> LDS
#pragma unroll
            for (int c = 0; c < 4; c++) {
                const float* g = (const float*)Xv + (m0 + rr[c]) * 1024 + kt + lb[c] * 8;
                const float4 lo = *(const float4*)g;
                const float4 hi = *(const float4*)(g + 4);
                *(uint4*)&As[(c * 256 + t) * 8] = pack8(lo, hi);
            }
        } else {                            // A: async DMA (R9: bf16 prepass path)
#pragma unroll
            for (int c = 0; c < 4; c++)
                async16((const u16*)Xv + (m0 + rr[c]) * 1024 + kt + lb[c] * 8,
                        &As[(c * 256 + t) * 8]);
        }
        __syncthreads();                    // (b) vmcnt drained + staging visible

#pragma unroll
        for (int kk = 0; kk < 64; kk += 32) {
            bf16x8 af[4], bfv[4];
#pragma unroll
            for (int i = 0; i < 4; i++) {
                const int ra = wm + i * 16 + l15;
                const int rb2 = wn + i * 16 + l15;
                af[i]  = *(const bf16x8*)&As[ra * 64 + (((kk >> 3) + quad) ^ (l15 & 7)) * 8];
                bfv[i] = *(const bf16x8*)&Bs[rb2 * 64 + (((kk >> 3) + quad) ^ (l15 & 7)) * 8];
            }
#pragma unroll
            for (int i = 0; i < 4; i++)
#pragma unroll
                for (int j = 0; j < 4; j++)
                    acc[i][j] = __builtin_amdgcn_mfma_f32_16x16x32_bf16(af[i], bfv[j], acc[i][j], 0, 0, 0);
        }
    }

    // epilogue: C row = quad*4 + r, col = lane&15 (HW-verified R4)
#pragma unroll
    for (int i = 0; i < 4; i++) {
        const int rb = m0 + wm + i * 16 + quad * 4;
#pragma unroll
        for (int j = 0; j < 4; j++) {
            const int col = n0 + wn + j * 16 + l15;
            const float bias_v = bias[col];
            if (mode == 2) {
                // V^T direct store: 4 consecutive s at fixed (h,d) -> packed b64
                const int b = rb >> 11, s = rb & 2047;
                const int h = col >> 6, d = col & 63;
                uint2 pk;
                pk.x = pk2(acc[i][j][0] + bias_v, acc[i][j][1] + bias_v);
                pk.y = pk2(acc[i][j][2] + bias_v, acc[i][j][3] + bias_v);
                *(uint2*)&dstb[((b * 16 + h) * 64 + d) * 2048 + s] = pk;
            } else {
#pragma unroll
                for (int r = 0; r < 4; r++) {
                    const float v = acc[i][j][r] + bias_v;
                    const int gm = rb + r;
                    if (mode == 0) {
                        const int b = gm >> 11, s = gm & 2047;
                        const int h = col >> 6, d = col & 63;
                        dstb[((b * 16 + h) * 2048 + s) * 64 + d] = f2b(v);
                    } else {
                        dstf[gm * 1024 + col] = v;
                    }
                }
            }
        }
    }
}

// R9: f32 -> bf16 convert prepass (memory-bound, ~150 MB total traffic).
__global__ __launch_bounds__(256)
void convert_x(const float* __restrict__ q_in, const float* __restrict__ k_in,
               const float* __restrict__ v_in, u16* __restrict__ Xb)
{
    const int z = blockIdx.y;
    const float* src = (z == 0) ? q_in : (z == 1) ? k_in : v_in;
    u16* dst = Xb + z * (8 * 1024 * 1024);
    const int i = (blockIdx.x * 256 + threadIdx.x) * 8;
    const float4 lo = *(const float4*)(src + i);
    const float4 hi = *(const float4*)(src + i + 4);
    *(uint4*)(dst + i) = pack8(lo, hi);
}

__global__ __launch_bounds__(256)
void qkv_kernel_f32(const float* __restrict__ q_in, const float* __restrict__ k_in,
                    const float* __restrict__ v_in, const u16* __restrict__ WT,
                    const float* __restrict__ bq, const float* __restrict__ bk,
                    const float* __restrict__ bv,
                    u16* __restrict__ Qo, u16* __restrict__ Ko, u16* __restrict__ VTo)
{
    const int z = blockIdx.z;
    const float* X   = (z == 0) ? q_in : (z == 1) ? k_in : v_in;
    const u16* wt    = WT + ((z == 0) ? 2 : (z == 1) ? 1 : 0) * (1024 * 1024);
    const float* bias= (z == 0) ? bq : (z == 1) ? bk : bv;
    u16* dst         = (z == 0) ? Qo : (z == 1) ? Ko : VTo;
    gemm128<true>(X, wt, bias, dst, nullptr, (z == 2) ? 2 : 0);
}

// R9: all-async16 qkv reading pre-converted bf16 X
__global__ __launch_bounds__(256)
void qkv_kernel_b16(const u16* __restrict__ Xb, const u16* __restrict__ WT,
                    const float* __restrict__ bq, const float* __restrict__ bk,
                    const float* __restrict__ bv,
                    u16* __restrict__ Qo, u16* __restrict__ Ko, u16* __restrict__ VTo)
{
    const int z = blockIdx.z;
    const u16* X     = Xb + z * (8 * 1024 * 1024);
    const u16* wt    = WT + ((z == 0) ? 2 : (z == 1) ? 1 : 0) * (1024 * 1024);
    const float* bias= (z == 0) ? bq : (z == 1) ? bk : bv;
    u16* dst         = (z == 0) ? Qo : (z == 1) ? Ko : VTo;
    gemm128<false>(X, wt, bias, dst, nullptr, (z == 2) ? 2 : 0);
}

__global__ __launch_bounds__(256)
void oproj_kernel(const u16* __restrict__ AO, const u16* __restrict__ WT,
                  const float* __restrict__ bo, float* __restrict__ out)
{
    gemm128<false>(AO, WT + 3 * 1024 * 1024, bo, nullptr, out, 1);
}

// ---------------- weight transpose+cvt: W[1024 k][1024 n] f32 -> WT[n][k] bf16 ----
__global__ void transpose_w(const float* __restrict__ Wv, const float* __restrict__ Wk,
                            const float* __restrict__ Wq, const float* __restrict__ Wo,
                            u16* __restrict__ WT)
{
    __shared__ u16 tile[64][65];
    const int z = blockIdx.z;
    const float* W = (z == 0) ? Wv : (z == 1) ? Wk : (z == 2) ? Wq : Wo;
    u16* dst = WT + z * 1024 * 1024;
    const int r0 = blockIdx.y * 64, c0 = blockIdx.x * 64;
    const int col = threadIdx.x & 63, rb = threadIdx.x >> 6;
#pragma unroll
    for (int r = rb; r < 64; r += 4) tile[r][col] = f2b(W[(r0 + r) * 1024 + c0 + col]);
    __syncthreads();
#pragma unroll
    for (int r = rb; r < 64; r += 4) dst[(c0 + r) * 1024 + r0 + col] = tile[col][r];
}

// ---------------- flash attention (transposed): Tq=64/block, Tk=128 KV tiles -------
// S^T = K·Q^T -> per-lane online softmax (lane owns one q-row via l15).
// K/V staged via async16 into unpadded XOR-swizzled LDS. O^T = V^T·P^T.
// R6: Q lives in 8 VGPRs/lane. R7: Ps ALIASES Ks (barrier (c)). R8: bounds (256,4)
// fixed R7's spill. R10: addr-hoist NEUTRAL (allocator already fine at 64 VGPR) ->
// attn is VALU-throughput-bound (~690 cy VALU/wave/iter, VALUBusy 67%).
// R11: three VALU cuts:
//  1. C-init = -m_st: MFMA's C-in does S-m for free (kills 32 v_sub/iter).
//  2. T13 defer-max THR=8 (exp2 domain): m_st starts 0; rescale only on
//     __any(col_max > 8). Non-breach iters skip alpha/rescale/m-update AND the
//     exp2s no longer depend on this tile's max (critical path cut). Safe:
//     P <= 2^8, l <= 2048*256 in f32.
//  3. Row-sum via ones-row MFMA: Vts -> [80][128]; row 64 = 1.0, 65..79 = 0
//     (constant rows are swizzle-invariant, written once). 5th dj slice in PV
//     accumulates l into o[4] with the same alpha chain (kills 32 adds + 2
//     shfl/iter); epilogue: one __shfl(o[4][0], l15).
__global__ __launch_bounds__(256, 3)
void attn_kernel(const u16* __restrict__ Q, const u16* __restrict__ K,
                 const u16* __restrict__ VT, u16* __restrict__ AO)
{
    __shared__ __align__(16) u16 KPs[128 * 64];   // Ks (swizzle r&7) / Ps (swizzle r&15)
    __shared__ __align__(16) u16 Vts[80 * 128];   // rows 0..63: V^T (swizzle r&15);
                                                  // row 64: ones, 65..79: zeros

    const int t    = threadIdx.x;
    const int lane = t & 63;
    const int wave = t >> 6;
    const int quad = lane >> 4;
    const int l15  = lane & 15;
    const int bh = blockIdx.y;
    const int qt = blockIdx.x;

    const u16* Qg = Q + (bh * 2048 + qt * 64) * 64;
    const u16* Kg = K + bh * 2048 * 64;
    const u16* Vg = VT + bh * 64 * 2048;

    // ones/zeros rows for the row-sum MFMA slice (written once; constant rows are
    // invariant under the column-block swizzle used by the dj reads)
    {
        const int idx = t * 8;                 // 2048 u16 over 256 threads
        const int row = 64 + (idx >> 7);
        const u16 one = 0x3F80;                // bf16 1.0
        u16 vals[8];
#pragma unroll
        for (int i = 0; i < 8; i++) vals[i] = (row == 64) ? one : (u16)0;
        *(uint4*)&Vts[64 * 128 + idx] = *(uint4*)vals;
    }

    // Q fragments in registers (fold 0.125*log2e -> exp2 domain)
    bf16x8 bqr[2];
    {
        const u16* qrow = Qg + (wave * 16 + l15) * 64 + quad * 8;
#pragma unroll
        for (int c = 0; c < 2; c++) {
            uint4 dv = *(const uint4*)(qrow + c * 32);
            u16 tmp[8];
            *(uint4*)tmp = dv;
            float f[8];
#pragma unroll
            for (int i = 0; i < 8; i++) {
                union { float f; uint32_t u; } x; x.u = ((uint32_t)tmp[i]) << 16;
                f[i] = x.f * 0.18033688f;   // 0.125 * log2e
            }
            uint4 pk;
            pk.x = pk2(f[0], f[1]); pk.y = pk2(f[2], f[3]);
            pk.z = pk2(f[4], f[5]); pk.w = pk2(f[6], f[7]);
            bqr[c] = *(bf16x8*)&pk;
        }
    }

    f32x4 o[5];                                // o[4] = online l (ones-row slice)
#pragma unroll
    for (int dj = 0; dj < 5; dj++)
#pragma unroll
        for (int r = 0; r < 4; r++) o[dj][r] = 0.0f;
    float m_st = 0.0f;                         // T13: defer-max, start at 0

    // hoisted staging maps: running global src pointers + fixed LDS dests
    const u16* kgp[4];
    const u16* vgp[4];
    u16* kld[4];
    u16* vld[4];
#pragma unroll
    for (int c = 0; c < 4; c++) {
        const int ci = c * 256 + t;
        const int krr = ci >> 3, klb = (ci & 7)  ^ (krr & 7);
        const int vrr = ci >> 4, vlb = (ci & 15) ^ (vrr & 15);
        kgp[c] = Kg + krr * 64 + klb * 8;      // += 128*64 per iter
        vgp[c] = Vg + vrr * 2048 + vlb * 8;    // += 128 per iter
        kld[c] = &KPs[ci * 8];
        vld[c] = &Vts[ci * 8];
    }
    // QK^T A-frag LDS offsets (u16 units): [kk/32][n]
    int ak_off[2][8];
#pragma unroll
    for (int ki = 0; ki < 2; ki++)
#pragma unroll
        for (int n = 0; n < 8; n++)
            ak_off[ki][n] = (n * 16 + l15) * 64 + (((ki * 4) + quad) ^ (l15 & 7)) * 8;
    // PV offsets: av [ks][dj] (dj 0..4), bp [ks]; P-write offsets pw [n]
    int av_off[4][5], bp_off[4], pw_off[8];
#pragma unroll
    for (int ks = 0; ks < 4; ks++) {
        bp_off[ks] = (wave * 16 + l15) * 128 + ((ks * 4 + quad) ^ l15) * 8;
#pragma unroll
        for (int dj = 0; dj < 5; dj++)
            av_off[ks][dj] = (dj * 16 + l15) * 128 + ((ks * 4 + quad) ^ l15) * 8;
    }
#pragma unroll
    for (int n = 0; n < 8; n++)
        pw_off[n] = (wave * 16 + l15) * 128 + ((2 * n + (quad >> 1)) ^ l15) * 8
                    + (quad & 1) * 4;

    for (int kv = 0; kv < 16; kv++) {
        __syncthreads();   // (a) prev tile's PV reads (KPs-as-Ps, Vts) done; also
                           //     orders the ones-row init before iter-0 staging
#pragma unroll
        for (int c = 0; c < 4; c++) {
            async16(kgp[c], kld[c]);
            async16(vgp[c], vld[c]);
        }
        __syncthreads();   // (b) DMA drained (vmcnt 0 before barrier) + visible

        // S^T = K·Q^T, accumulator pre-loaded with -m_st (free S-m subtraction)
        f32x4 s[8];
#pragma unroll
        for (int n = 0; n < 8; n++)
#pragma unroll
            for (int r = 0; r < 4; r++) s[n][r] = -m_st;
#pragma unroll
        for (int ki = 0; ki < 2; ki++) {
            const bf16x8 bq = bqr[ki];
#pragma unroll
            for (int n = 0; n < 8; n++) {
                const bf16x8 ak = *(const bf16x8*)&KPs[ak_off[ki][n]];
                s[n] = __builtin_amdgcn_mfma_f32_16x16x32_bf16(ak, bq, s[n], 0, 0, 0);
            }
        }
        __syncthreads();   // (c) ALL waves' Ks reads done before Ps overwrites KPs

        // column max (s domain); rescale ONLY on threshold breach (T13)
        float mxn[8];
#pragma unroll
        for (int n = 0; n < 8; n++)
            mxn[n] = fmaxf(fmaxf(s[n][0], s[n][1]), fmaxf(s[n][2], s[n][3]));
        float mx = fmaxf(fmaxf(fmaxf(mxn[0], mxn[1]), fmaxf(mxn[2], mxn[3])),
                         fmaxf(fmaxf(mxn[4], mxn[5]), fmaxf(mxn[6], mxn[7])));
        mx = fmaxf(mx, __shfl_xor(mx, 16));
        mx = fmaxf(mx, __shfl_xor(mx, 32));
        if (__any(mx > 8.0f)) {                // rare: only when tile max grows >8
            const float dm = fmaxf(mx, 0.0f);  // per-column monotone bump
            const float alpha = exp2f(-dm);
#pragma unroll
            for (int n = 0; n < 8; n++)
#pragma unroll
                for (int r = 0; r < 4; r++) s[n][r] -= dm;
            m_st += dm;
#pragma unroll
            for (int dj = 0; dj < 5; dj++)
#pragma unroll
                for (int r = 0; r < 4; r++) o[dj][r] *= alpha;
        }

        // P = exp2(s) -> packed bf16 -> swizzled LDS (aliasing Ks)
#pragma unroll
        for (int n = 0; n < 8; n++) {
            uint2 pk;
            pk.x = pk2(exp2f(s[n][0]), exp2f(s[n][1]));
            pk.y = pk2(exp2f(s[n][2]), exp2f(s[n][3]));
            *(uint2*)&KPs[pw_off[n]] = pk;
        }
        asm volatile("s_waitcnt lgkmcnt(0)" ::: "memory");  // wave-private RAW fence

        // O^T += V^T·P^T  (dj=4 is the ones-row slice: accumulates l into o[4])
#pragma unroll
        for (int ks = 0; ks < 4; ks++) {
            const bf16x8 bp = *(const bf16x8*)&KPs[bp_off[ks]];
#pragma unroll
            for (int dj = 0; dj < 5; dj++) {
                const bf16x8 av = *(const bf16x8*)&Vts[av_off[ks][dj]];
                o[dj] = __builtin_amdgcn_mfma_f32_16x16x32_bf16(av, bp, o[dj], 0, 0, 0);
            }
        }

#pragma unroll
        for (int c = 0; c < 4; c++) {
            kgp[c] += 128 * 64;
            vgp[c] += 128;
        }
    }

    // epilogue: l for column q=l15 lives in lane (quad 0, l15), reg 0 of o[4]
    const float lsum = __shfl(o[4][0], l15);
    const int b = bh >> 4, h = bh & 15;
    const int sq = qt * 64 + wave * 16 + l15;
    const float inv = 1.0f / lsum;
#pragma unroll
    for (int dj = 0; dj < 4; dj++) {
        uint2 pk;
        pk.x = pk2(o[dj][0] * inv, o[dj][1] * inv);
        pk.y = pk2(o[dj][2] * inv, o[dj][3] * inv);
        *(uint2*)&AO[(b * 2048 + sq) * 1024 + h * 64 + dj * 16 + quad * 4] = pk;
    }
}

extern "C" void kernel_launch(void* const* d_in, const int* in_sizes, int n_in,
                              void* d_out, int out_size, void* d_ws, size_t ws_size,
                              hipStream_t stream)
{
    (void)in_sizes; (void)n_in; (void)out_size;
    const float* value = (const float*)d_in[0];
    const float* key_  = (const float*)d_in[1];
    const float* query = (const float*)d_in[2];
    const float* Wv = (const float*)d_in[3];
    const float* bv = (const float*)d_in[4];
    const float* Wk = (const float*)d_in[5];
    const float* bk = (const float*)d_in[6];
    const float* Wq = (const float*)d_in[7];
    const float* bq = (const float*)d_in[8];
    const float* Wo = (const float*)d_in[9];
    const float* bo = (const float*)d_in[10];

    u16* ws = (u16*)d_ws;
    u16* WT = ws;                          // 4 x 1M bf16 (order: v,k,q,o)
    u16* Q  = ws + 4 * 1024 * 1024;        // 8M bf16 [B,H,S,D]
    u16* K  = Q + 8 * 1024 * 1024;         // 8M [B,H,S,D]
    u16* VT = K + 8 * 1024 * 1024;         // 8M [B,H,D,S] (written directly by qkv)
    u16* AO = VT + 8 * 1024 * 1024;        // 8M [B*S, E]   (72 MB so far)
    u16* Xb = AO + 8 * 1024 * 1024;        // 3 x 8M bf16 converted inputs (q,k,v)
    const size_t need = (size_t)(4 + 8 + 8 + 8 + 8 + 24) * 1024 * 1024 * sizeof(u16);

    transpose_w<<<dim3(16, 16, 4), dim3(256), 0, stream>>>(Wv, Wk, Wq, Wo, WT);
    if (ws_size >= need) {
        convert_x<<<dim3(4096, 3), dim3(256), 0, stream>>>(query, key_, value, Xb);
        qkv_kernel_b16<<<dim3(8, 64, 3), dim3(256), 0, stream>>>(Xb, WT, bq, bk, bv,
                                                                 Q, K, VT);
    } else {
        qkv_kernel_f32<<<dim3(8, 64, 3), dim3(256), 0, stream>>>(query, key_, value,
                                                                 WT, bq, bk, bv,
                                                                 Q, K, VT);
    }
    attn_kernel<<<dim3(32, 64), dim3(256), 0, stream>>>(Q, K, VT, AO);
    oproj_kernel<<<dim3(8, 64, 1), dim3(256), 0, stream>>>(AO, WT, bo, (float*)d_out);
}